// Round 5
// baseline (9596.277 us; speedup 1.0000x reference)
//
#include <hip/hip_runtime.h>
#include <math.h>

// RewardGuidanceModel: 8-layer Mamba2 stack, B=4096, L=17, fully fused.
// One workgroup (256 thr) per batch element; all activations in LDS/regs.
// R8: scan register diet to make launch_bounds(256,4)'s HARD 64-VGPR budget
// spill-free. Empirical hipcc law (R0/R4/R5/R6/R7): maxVGPR = 256/n rounded
// to granule (n=3->84, n=4->64, n=6->40). R7's scan peaked ~62-66 live
// (acc1[17]+y17[17]+hst[16]+transients) -> partial spill, ~5.5 GB scratch.
// R8 changes ONLY phase 4:
//  - pre-fold: y17[t]=acc1[t]*Dsk; acc1[t]*=dtv  (acc1 becomes xd; kills
//    dtv/xd transients and the last-pass special case)
//  - 4 passes x 8 states (hst[8]): live = 42 + ~12 transients ~ 54-58 < 64
// LDS layout (27136 B), z-in-d_out parking, barriers: identical to R7.
// Fallback if hbm_bytes stays >5 GB: (256,2) next round.

#define BATCH 4096
#define LSEQ 17
#define DM 128
#define DIN 324
#define DINNER 256
#define DSTATE 32
#define NH 32
#define NL 8
#define DPROJ 608
#define EPSF 1e-5f

#define OFF_WT 0
#define SZ_WT (NL * DM * DPROJ)
#define OFF_OWT (OFF_WT + SZ_WT)
#define SZ_OWT (NL * DINNER * DM)
#define OFF_IWT (OFF_OWT + SZ_OWT)
#define SZ_IWT (DIN * 64)
#define OFF_OUTWT (OFF_IWT + SZ_IWT)
#define SZ_OUTWT (DM * DIN)
#define WS_TOTAL (OFF_OUTWT + SZ_OUTWT)

// LDS layout (floats). Region [2176, 6784) is time-shared:
//   phases 1-2: XN  (128 rows x stride 18 = 2304)   [2176, 4480)
//   phases 3-4: BC2 (17*64=1088) DTT(544) AT(544)   [4480, 6656)
//   phases 5-7: G2  (256 rows x stride 18 = 4608)   [2176, 6784)
// Barrier (d) between scan reads and G2 writes makes the overlay safe.
#define XMAT 0
#define XN   2176
#define G2   2176
#define BC2  4480
#define DTT  5568
#define AT   6112
#define STG  0
#define SMEM_TOT 6784

__device__ __forceinline__ float siluf(float x) { return x / (1.f + __expf(-x)); }

__global__ void prep_weights(const float* __restrict__ in_proj_w,
                             const float* __restrict__ out_proj_w,
                             const float* __restrict__ mixer_norm_w,
                             const float* __restrict__ input_w,
                             const float* __restrict__ output_w,
                             float* __restrict__ ws) {
    int idx = blockIdx.x * 256 + threadIdx.x;
    if (idx < SZ_WT) {
        int l = idx / (DM * DPROJ);
        int r = idx - l * (DM * DPROJ);
        int d = r / DPROJ, j = r - d * DPROJ;
        ws[OFF_WT + idx] = in_proj_w[(l * DPROJ + j) * DM + d];
    } else if (idx < OFF_IWT) {
        int r2 = idx - OFF_OWT;
        int l = r2 / (DINNER * DM);
        int r = r2 - l * (DINNER * DM);
        int in_ = r / DM, o = r - in_ * DM;
        ws[idx] = out_proj_w[(l * DM + o) * DINNER + in_] * mixer_norm_w[l * DINNER + in_];
    } else if (idx < OFF_OUTWT) {
        int r = idx - OFF_IWT;
        int d = r / 64, o = r - d * 64;
        ws[idx] = input_w[o * DIN + d];
    } else if (idx < WS_TOTAL) {
        int r = idx - OFF_OUTWT;
        int d = r / DIN, o = r - d * DIN;
        ws[idx] = output_w[o * DM + d];
    }
}

__global__ __launch_bounds__(256, 4)
void mamba_all(const float* __restrict__ ini, const float* __restrict__ fut,
               const float* __restrict__ tflag, const float* __restrict__ sval,
               const float* __restrict__ input_b, const float* __restrict__ states_emb,
               const float* __restrict__ time_w, const float* __restrict__ time_b,
               const float* __restrict__ short_w, const float* __restrict__ short_b,
               const float* __restrict__ conv_w, const float* __restrict__ conv_b,
               const float* __restrict__ dt_bias, const float* __restrict__ A_log,
               const float* __restrict__ D_skip, const float* __restrict__ layer_norm_w,
               const float* __restrict__ output_b, const float* __restrict__ ws,
               float* __restrict__ out) {
    __shared__ float S[SMEM_TOT];
    const int tid = threadIdx.x;
    const int b = blockIdx.x;
    const int lane = tid & 63;
    const int wid = tid >> 6;

    const float tf = tflag[b];
    const float sv = sval[b];

    // per-block z-scratch inside d_out (4352 of 5184 floats; epilogue overwrites)
    float* zbuf = out + (size_t)b * (16 * DIN);

    // ---------- prologue: stage raw inputs ----------
    {
        const float* ir = ini + (size_t)b * DIN;
        const float* fr = fut + (size_t)b * 16 * DIN;
        for (int i = tid; i < DIN; i += 256) S[STG + i] = ir[i];
        for (int i = tid; i < 16 * DIN; i += 256) S[STG + DIN + i] = fr[i];
    }
    __syncthreads();
    // input projection (17x64); results in registers, written after barrier
    float ipacc[5]; float ipemb[5];
    int ipn = 0;
    {
        const float* iwT = ws + OFF_IWT;
        for (int idx = tid; idx < LSEQ * 64; idx += 256) {
            int t = idx >> 6, o = idx & 63;
            float acc = input_b[o];
            const float* sr = &S[STG + t * DIN];
            for (int d = 0; d < DIN; d += 4) {
                float4 sq = *reinterpret_cast<const float4*>(sr + d);
                acc = fmaf(sq.x, iwT[d * 64 + o], acc);
                acc = fmaf(sq.y, iwT[(d + 1) * 64 + o], acc);
                acc = fmaf(sq.z, iwT[(d + 2) * 64 + o], acc);
                acc = fmaf(sq.w, iwT[(d + 3) * 64 + o], acc);
            }
            ipacc[ipn] = acc;
            ipemb[ipn] = states_emb[t * 64 + o];
            ipn++;
        }
    }
    __syncthreads();
    {
        int k = 0;
        for (int idx = tid; idx < LSEQ * 64; idx += 256) {
            int t = idx >> 6, o = idx & 63;
            S[XMAT + t * DM + 64 + o] = ipacc[k];
            S[XMAT + t * DM + o] = ipemb[k];
            k++;
        }
    }
    __syncthreads();
    // te/se modulation (first halves)
    for (int idx = tid; idx < LSEQ * DM; idx += 256) {
        int d = idx & 127;
        float te0 = fmaf(tf, time_w[d], time_b[d]);
        float te1 = fmaf(tf, time_w[128 + d], time_b[128 + d]);
        float se0 = fmaf(sv, short_w[d], short_b[d]);
        float se1 = fmaf(sv, short_w[128 + d], short_b[128 + d]);
        S[XMAT + idx] = S[XMAT + idx] * te0 * se0 + te1 + se1;
    }

    const int h = tid >> 3;

    // ---------- 8 mamba2 layers ----------
    for (int l = 0; l < NL; ++l) {
        __syncthreads();   // (a) XMAT settled, prev-layer G2 reads done
        // phase 1: rmsnorm(x) -> XN [d][t] stride 18
        {
            const float* lnw = layer_norm_w + l * DM;
            for (int r = wid; r < LSEQ; r += 4) {
                float x0 = S[XMAT + r * DM + lane];
                float x1 = S[XMAT + r * DM + 64 + lane];
                float ss = x0 * x0 + x1 * x1;
                #pragma unroll
                for (int off = 1; off < 64; off <<= 1) ss += __shfl_xor(ss, off, 64);
                float rs = rsqrtf(ss * (1.f / 128.f) + EPSF);
                S[XN + lane * 18 + r] = x0 * rs * lnw[lane];
                S[XN + (64 + lane) * 18 + r] = x1 * rs * lnw[64 + lane];
            }
        }
        __syncthreads();   // (b)

        // phase 2, pass A: z (acc0) and xs (acc1) columns, all threads.
        // float2 LDS loads consumed directly (no xv[] temp array).
        float acc0[17], acc1[17];
        #pragma unroll
        for (int t = 0; t < 17; ++t) { acc0[t] = 0.f; acc1[t] = 0.f; }
        {
            const float* wl = ws + OFF_WT + l * (DM * DPROJ);
            for (int d = 0; d < DM; ++d) {
                float w0 = wl[d * DPROJ + tid];
                float w1 = wl[d * DPROJ + 256 + tid];
                const float* xr = &S[XN + d * 18];
                #pragma unroll
                for (int tt = 0; tt < 8; ++tt) {
                    float2 p = *reinterpret_cast<const float2*>(xr + 2 * tt);
                    acc0[2*tt]   = fmaf(p.x, w0, acc0[2*tt]);
                    acc1[2*tt]   = fmaf(p.x, w1, acc1[2*tt]);
                    acc0[2*tt+1] = fmaf(p.y, w0, acc0[2*tt+1]);
                    acc1[2*tt+1] = fmaf(p.y, w1, acc1[2*tt+1]);
                }
                float x16 = xr[16];
                acc0[16] = fmaf(x16, w0, acc0[16]);
                acc1[16] = fmaf(x16, w1, acc1[16]);
            }
        }
        // park silu(z) in global scratch (frees acc0 before pass B/scan)
        {
            float* zb = zbuf + tid;
            #pragma unroll
            for (int t = 0; t < 17; ++t) zb[t * 256] = siluf(acc0[t]);
        }
        // phase 2, pass B: B/C/dt columns (acc2), waves 0-1 only
        float acc2[17];
        #pragma unroll
        for (int t = 0; t < 17; ++t) acc2[t] = 0.f;
        if (tid < 128) {
            const float* wl = ws + OFF_WT + l * (DM * DPROJ);
            const bool has2 = (tid < 96);
            for (int d = 0; d < DM; ++d) {
                float w2 = has2 ? wl[d * DPROJ + 512 + tid] : 0.f;
                const float* xr = &S[XN + d * 18];
                #pragma unroll
                for (int tt = 0; tt < 8; ++tt) {
                    float2 p = *reinterpret_cast<const float2*>(xr + 2 * tt);
                    acc2[2*tt]   = fmaf(p.x, w2, acc2[2*tt]);
                    acc2[2*tt+1] = fmaf(p.y, w2, acc2[2*tt+1]);
                }
                acc2[16] = fmaf(xr[16], w2, acc2[16]);
            }
        }

        // phase 3: conv IN PLACE into acc1 (descending t: inputs t-3..t are
        // only overwritten at indices > t) -> acc1 becomes silu-conv'd xs.
        {
            const float* cw = conv_w + l * 320 * 4;
            const float* cb = conv_b + l * 320;
            {
                float k0 = cw[tid * 4 + 0], k1 = cw[tid * 4 + 1];
                float k2 = cw[tid * 4 + 2], k3 = cw[tid * 4 + 3];
                float bias = cb[tid];
                #pragma unroll
                for (int t = 16; t >= 0; --t) {
                    float s = fmaf(acc1[t], k3, bias);
                    if (t >= 1) s = fmaf(acc1[t - 1], k2, s);
                    if (t >= 2) s = fmaf(acc1[t - 2], k1, s);
                    if (t >= 3) s = fmaf(acc1[t - 3], k0, s);
                    acc1[t] = siluf(s);
                }
            }
            if (tid < 64) {
                int c = 256 + tid;
                float k0 = cw[c * 4 + 0], k1 = cw[c * 4 + 1];
                float k2 = cw[c * 4 + 2], k3 = cw[c * 4 + 3];
                float bias = cb[c];
                #pragma unroll
                for (int t = 0; t < 17; ++t) {
                    float s = fmaf(acc2[t], k3, bias);
                    if (t >= 1) s = fmaf(acc2[t - 1], k2, s);
                    if (t >= 2) s = fmaf(acc2[t - 2], k1, s);
                    if (t >= 3) s = fmaf(acc2[t - 3], k0, s);
                    S[BC2 + t * 64 + tid] = siluf(s);
                }
            } else if (tid < 96) {
                int hh = tid - 64;
                float dtb = dt_bias[l * NH + hh];
                float eA = __expf(A_log[l * NH + hh]);
                #pragma unroll
                for (int t = 0; t < 17; ++t) {
                    float v = acc2[t] + dtb;
                    float dtv = (v > 15.f) ? v : log1pf(__expf(v));
                    S[DTT + hh * 17 + t] = dtv;
                    S[AT + hh * 17 + t] = __expf(-eA * dtv);
                }
            }
        }
        __syncthreads();   // (c)

        // phase 4: selective scan, 4 passes x 8 states, D_skip/dt pre-folded.
        // Live set: acc1[17](=xd) + y17[17] + hst[8] = 42 + ~12 transients.
        float y17[17];
        {
            const float Dsk = D_skip[l * NH + h];
            #pragma unroll
            for (int t = 0; t < 17; ++t) {
                y17[t] = acc1[t] * Dsk;              // D-skip term (uses xs)
                acc1[t] *= S[DTT + h * 17 + t];      // acc1 becomes xd
            }
        }
        #pragma unroll
        for (int qp = 0; qp < 4; ++qp) {
            float hst[8];
            #pragma unroll
            for (int n = 0; n < 8; ++n) hst[n] = 0.f;
            #pragma unroll
            for (int t = 0; t < 17; ++t) {
                float at = S[AT + h * 17 + t];
                float xd = acc1[t];
                float y = y17[t];
                const float4* bq = reinterpret_cast<const float4*>(&S[BC2 + t * 64]);
                {
                    float4 bb = bq[2 * qp];
                    hst[0] = fmaf(at, hst[0], xd * bb.x);
                    hst[1] = fmaf(at, hst[1], xd * bb.y);
                    hst[2] = fmaf(at, hst[2], xd * bb.z);
                    hst[3] = fmaf(at, hst[3], xd * bb.w);
                    float4 cc = bq[8 + 2 * qp];
                    y = fmaf(hst[0], cc.x, y);
                    y = fmaf(hst[1], cc.y, y);
                    y = fmaf(hst[2], cc.z, y);
                    y = fmaf(hst[3], cc.w, y);
                }
                {
                    float4 bb = bq[2 * qp + 1];
                    hst[4] = fmaf(at, hst[4], xd * bb.x);
                    hst[5] = fmaf(at, hst[5], xd * bb.y);
                    hst[6] = fmaf(at, hst[6], xd * bb.z);
                    hst[7] = fmaf(at, hst[7], xd * bb.w);
                    float4 cc = bq[8 + 2 * qp + 1];
                    y = fmaf(hst[4], cc.x, y);
                    y = fmaf(hst[5], cc.y, y);
                    y = fmaf(hst[6], cc.z, y);
                    y = fmaf(hst[7], cc.w, y);
                }
                y17[t] = y;
            }
        }
        __syncthreads();   // (d) all scan reads of BC2/DTT/AT done -> G2 may overwrite
        // phase 5: G2 = silu(z) * y ; z reload fused into the store (no zv[])
        {
            const float* zb = zbuf + tid;
            #pragma unroll
            for (int t = 0; t < 17; ++t) {
                S[G2 + tid * 18 + t] = zb[t * 256] * y17[t];
            }
        }
        __syncthreads();   // (e)
        // phase 6: per-row sumsq -> scale G2 in place (folds RS away)
        for (int r = wid; r < LSEQ; r += 4) {
            float g0 = S[G2 + lane * 18 + r];
            float g1 = S[G2 + (64 + lane) * 18 + r];
            float g2v = S[G2 + (128 + lane) * 18 + r];
            float g3 = S[G2 + (192 + lane) * 18 + r];
            float ss = g0 * g0 + g1 * g1 + g2v * g2v + g3 * g3;
            #pragma unroll
            for (int off = 1; off < 64; off <<= 1) ss += __shfl_xor(ss, off, 64);
            float rs = rsqrtf(ss * (1.f / 256.f) + EPSF);
            S[G2 + lane * 18 + r] = g0 * rs;
            S[G2 + (64 + lane) * 18 + r] = g1 * rs;
            S[G2 + (128 + lane) * 18 + r] = g2v * rs;
            S[G2 + (192 + lane) * 18 + r] = g3 * rs;
        }
        __syncthreads();   // (f)
        // phase 7: out_proj + residual
        {
            const int o = tid & 127;
            const int half = tid >> 7;
            const int t0 = half ? 8 : 0;
            float acc[9];
            #pragma unroll
            for (int k = 0; k < 9; ++k) acc[k] = 0.f;
            const float* ow = ws + OFF_OWT + l * (DINNER * DM);
            for (int in = 0; in < DINNER; ++in) {
                float w = ow[in * DM + o];
                const float* gr = &S[G2 + in * 18 + t0];
                float2 g0 = *reinterpret_cast<const float2*>(gr);
                float2 g1 = *reinterpret_cast<const float2*>(gr + 2);
                float2 g2v = *reinterpret_cast<const float2*>(gr + 4);
                float2 g3 = *reinterpret_cast<const float2*>(gr + 6);
                acc[0] = fmaf(g0.x, w, acc[0]); acc[1] = fmaf(g0.y, w, acc[1]);
                acc[2] = fmaf(g1.x, w, acc[2]); acc[3] = fmaf(g1.y, w, acc[3]);
                acc[4] = fmaf(g2v.x, w, acc[4]); acc[5] = fmaf(g2v.y, w, acc[5]);
                acc[6] = fmaf(g3.x, w, acc[6]); acc[7] = fmaf(g3.y, w, acc[7]);
                if (half) acc[8] = fmaf(gr[8], w, acc[8]);
            }
            const int nt = half ? 9 : 8;
            for (int k = 0; k < nt; ++k) {
                int t = t0 + k;
                S[XMAT + t * DM + o] += acc[k];
            }
        }
    }

    // ---------- epilogue ----------
    __syncthreads();
    for (int idx = tid; idx < LSEQ * DM; idx += 256) {
        int d = idx & 127;
        float te2 = fmaf(tf, time_w[256 + d], time_b[256 + d]);
        float te3 = fmaf(tf, time_w[384 + d], time_b[384 + d]);
        float se2 = fmaf(sv, short_w[256 + d], short_b[256 + d]);
        float se3 = fmaf(sv, short_w[384 + d], short_b[384 + d]);
        S[XN + idx] = S[XMAT + idx] * te2 * se2 + te3 + se3;
    }
    __syncthreads();
    {
        const float* outwT = ws + OFF_OUTWT;
        float* orow = out + (size_t)b * 16 * DIN;
        for (int idx = tid; idx < 16 * DIN; idx += 256) {
            int t1 = idx / DIN;
            int o = idx - t1 * DIN;
            float acc = output_b[o];
            const float* xr = &S[XN + (t1 + 1) * DM];
            for (int d = 0; d < DM; d += 4) {
                float4 xq = *reinterpret_cast<const float4*>(xr + d);
                acc = fmaf(xq.x, outwT[d * DIN + o], acc);
                acc = fmaf(xq.y, outwT[(d + 1) * DIN + o], acc);
                acc = fmaf(xq.z, outwT[(d + 2) * DIN + o], acc);
                acc = fmaf(xq.w, outwT[(d + 3) * DIN + o], acc);
            }
            orow[idx] = acc;
        }
    }
}

extern "C" void kernel_launch(void* const* d_in, const int* in_sizes, int n_in,
                              void* d_out, int out_size, void* d_ws, size_t ws_size,
                              hipStream_t stream) {
    (void)in_sizes; (void)n_in; (void)out_size; (void)ws_size;
    const float* init_states    = (const float*)d_in[0];
    const float* future_states  = (const float*)d_in[1];
    const float* time_flags     = (const float*)d_in[2];
    const float* shortcut_value = (const float*)d_in[3];
    const float* input_w        = (const float*)d_in[4];
    const float* input_b        = (const float*)d_in[5];
    const float* states_emb     = (const float*)d_in[6];
    const float* time_w         = (const float*)d_in[7];
    const float* time_b         = (const float*)d_in[8];
    const float* short_w        = (const float*)d_in[9];
    const float* short_b        = (const float*)d_in[10];
    const float* in_proj_w      = (const float*)d_in[11];
    const float* conv_w         = (const float*)d_in[12];
    const float* conv_b         = (const float*)d_in[13];
    const float* dt_bias        = (const float*)d_in[14];
    const float* A_log          = (const float*)d_in[15];
    const float* D_skip         = (const float*)d_in[16];
    const float* mixer_norm_w   = (const float*)d_in[17];
    const float* out_proj_w     = (const float*)d_in[18];
    const float* layer_norm_w   = (const float*)d_in[19];
    const float* output_w       = (const float*)d_in[20];
    const float* output_b       = (const float*)d_in[21];
    float* ws = (float*)d_ws;
    float* outp = (float*)d_out;

    prep_weights<<<(WS_TOTAL + 255) / 256, 256, 0, stream>>>(
        in_proj_w, out_proj_w, mixer_norm_w, input_w, output_w, ws);
    mamba_all<<<BATCH, 256, 0, stream>>>(
        init_states, future_states, time_flags, shortcut_value,
        input_b, states_emb, time_w, time_b, short_w, short_b,
        conv_w, conv_b, dt_bias, A_log, D_skip, layer_norm_w,
        output_b, ws, outp);
}

// Round 7
// 6942.548 us; speedup vs baseline: 1.3822x; 1.3822x over previous
//
#include <hip/hip_runtime.h>
#include <math.h>

// RewardGuidanceModel: 8-layer Mamba2 stack, B=4096, L=17, fully fused.
// One workgroup (256 thr) per batch element; all activations in LDS/regs.
// R10 == R9 resubmit (previous round died on container acquire, not on the
// kernel). R9 rationale: phase reorder to make launch_bounds(256,4)'s hard
// 64-VGPR cap truly spill-free. Lesson from R4-R8 (all pinned at cap with
// GBs of scratch): the allocator spills whichever 17-long t-array crosses
// the peak; the fix is to never have more than {scan: acc1+y17+hst8} or
// {2Z: y17+acc0} co-live.
// Per-layer order:  2B(acc2)+convBC -> 2X(acc1)+conv-xs -> [c] ->
// scan(acc1 -> y17) -> 2Z(acc0, reads XN which is STILL VALID: XN region
// [2176,4480) is disjoint from BC2/DTT/AT [4480,6656)) -> [d] ->
// G2 = silu(acc0)*y17. This also ELIMINATES the z park/reload through
// d_out (1.1 GB + latency) entirely. Prologue ipacc runtime-index fixed
// (rule #20). LDS layout (27136 B) and phases 5-7 identical to R8.
// Fallback if hbm_bytes still > 4 GB: same kernel at (256,2).

#define BATCH 4096
#define LSEQ 17
#define DM 128
#define DIN 324
#define DINNER 256
#define DSTATE 32
#define NH 32
#define NL 8
#define DPROJ 608
#define EPSF 1e-5f

#define OFF_WT 0
#define SZ_WT (NL * DM * DPROJ)
#define OFF_OWT (OFF_WT + SZ_WT)
#define SZ_OWT (NL * DINNER * DM)
#define OFF_IWT (OFF_OWT + SZ_OWT)
#define SZ_IWT (DIN * 64)
#define OFF_OUTWT (OFF_IWT + SZ_IWT)
#define SZ_OUTWT (DM * DIN)
#define WS_TOTAL (OFF_OUTWT + SZ_OUTWT)

// LDS layout (floats). Region [2176, 6784) is time-shared:
//   phases 1-2Z: XN  (128 rows x stride 18 = 2304)  [2176, 4480)  (alive
//                through the scan and pass 2Z)
//   phases 3-4 : BC2 (17*64=1088) DTT(544) AT(544)  [4480, 6656)
//   phases 5-7 : G2  (256 rows x stride 18 = 4608)  [2176, 6784)
// Barrier (d) separates ALL XN/BC2/DTT/AT reads from the G2 overwrite.
#define XMAT 0
#define XN   2176
#define G2   2176
#define BC2  4480
#define DTT  5568
#define AT   6112
#define STG  0
#define SMEM_TOT 6784

__device__ __forceinline__ float siluf(float x) { return x / (1.f + __expf(-x)); }

__global__ void prep_weights(const float* __restrict__ in_proj_w,
                             const float* __restrict__ out_proj_w,
                             const float* __restrict__ mixer_norm_w,
                             const float* __restrict__ input_w,
                             const float* __restrict__ output_w,
                             float* __restrict__ ws) {
    int idx = blockIdx.x * 256 + threadIdx.x;
    if (idx < SZ_WT) {
        int l = idx / (DM * DPROJ);
        int r = idx - l * (DM * DPROJ);
        int d = r / DPROJ, j = r - d * DPROJ;
        ws[OFF_WT + idx] = in_proj_w[(l * DPROJ + j) * DM + d];
    } else if (idx < OFF_IWT) {
        int r2 = idx - OFF_OWT;
        int l = r2 / (DINNER * DM);
        int r = r2 - l * (DINNER * DM);
        int in_ = r / DM, o = r - in_ * DM;
        ws[idx] = out_proj_w[(l * DM + o) * DINNER + in_] * mixer_norm_w[l * DINNER + in_];
    } else if (idx < OFF_OUTWT) {
        int r = idx - OFF_IWT;
        int d = r / 64, o = r - d * 64;
        ws[idx] = input_w[o * DIN + d];
    } else if (idx < WS_TOTAL) {
        int r = idx - OFF_OUTWT;
        int d = r / DIN, o = r - d * DIN;
        ws[idx] = output_w[o * DM + d];
    }
}

__global__ __launch_bounds__(256, 4)
void mamba_all(const float* __restrict__ ini, const float* __restrict__ fut,
               const float* __restrict__ tflag, const float* __restrict__ sval,
               const float* __restrict__ input_b, const float* __restrict__ states_emb,
               const float* __restrict__ time_w, const float* __restrict__ time_b,
               const float* __restrict__ short_w, const float* __restrict__ short_b,
               const float* __restrict__ conv_w, const float* __restrict__ conv_b,
               const float* __restrict__ dt_bias, const float* __restrict__ A_log,
               const float* __restrict__ D_skip, const float* __restrict__ layer_norm_w,
               const float* __restrict__ output_b, const float* __restrict__ ws,
               float* __restrict__ out) {
    __shared__ float S[SMEM_TOT];
    const int tid = threadIdx.x;
    const int b = blockIdx.x;
    const int lane = tid & 63;
    const int wid = tid >> 6;

    const float tf = tflag[b];
    const float sv = sval[b];

    // ---------- prologue: stage raw inputs ----------
    {
        const float* ir = ini + (size_t)b * DIN;
        const float* fr = fut + (size_t)b * 16 * DIN;
        for (int i = tid; i < DIN; i += 256) S[STG + i] = ir[i];
        for (int i = tid; i < 16 * DIN; i += 256) S[STG + DIN + i] = fr[i];
    }
    __syncthreads();
    // input projection (17x64); results in registers (STATIC k index),
    // written to XMAT after the barrier.
    float ipacc[5]; float ipemb[5];
    {
        const float* iwT = ws + OFF_IWT;
        #pragma unroll
        for (int k = 0; k < 5; ++k) {
            int idx = tid + k * 256;
            ipacc[k] = 0.f; ipemb[k] = 0.f;
            if (idx < LSEQ * 64) {
                int t = idx >> 6, o = idx & 63;
                float acc = input_b[o];
                const float* sr = &S[STG + t * DIN];
                for (int d = 0; d < DIN; d += 4) {
                    float4 sq = *reinterpret_cast<const float4*>(sr + d);
                    acc = fmaf(sq.x, iwT[d * 64 + o], acc);
                    acc = fmaf(sq.y, iwT[(d + 1) * 64 + o], acc);
                    acc = fmaf(sq.z, iwT[(d + 2) * 64 + o], acc);
                    acc = fmaf(sq.w, iwT[(d + 3) * 64 + o], acc);
                }
                ipacc[k] = acc;
                ipemb[k] = states_emb[t * 64 + o];
            }
        }
    }
    __syncthreads();
    {
        #pragma unroll
        for (int k = 0; k < 5; ++k) {
            int idx = tid + k * 256;
            if (idx < LSEQ * 64) {
                int t = idx >> 6, o = idx & 63;
                S[XMAT + t * DM + 64 + o] = ipacc[k];
                S[XMAT + t * DM + o] = ipemb[k];
            }
        }
    }
    __syncthreads();
    // te/se modulation (first halves)
    for (int idx = tid; idx < LSEQ * DM; idx += 256) {
        int d = idx & 127;
        float te0 = fmaf(tf, time_w[d], time_b[d]);
        float te1 = fmaf(tf, time_w[128 + d], time_b[128 + d]);
        float se0 = fmaf(sv, short_w[d], short_b[d]);
        float se1 = fmaf(sv, short_w[128 + d], short_b[128 + d]);
        S[XMAT + idx] = S[XMAT + idx] * te0 * se0 + te1 + se1;
    }

    const int h = tid >> 3;

    // ---------- 8 mamba2 layers ----------
    for (int l = 0; l < NL; ++l) {
        __syncthreads();   // (a) XMAT settled, prev-layer G2 reads done
        // phase 1: rmsnorm(x) -> XN [d][t] stride 18
        {
            const float* lnw = layer_norm_w + l * DM;
            for (int r = wid; r < LSEQ; r += 4) {
                float x0 = S[XMAT + r * DM + lane];
                float x1 = S[XMAT + r * DM + 64 + lane];
                float ss = x0 * x0 + x1 * x1;
                #pragma unroll
                for (int off = 1; off < 64; off <<= 1) ss += __shfl_xor(ss, off, 64);
                float rs = rsqrtf(ss * (1.f / 128.f) + EPSF);
                S[XN + lane * 18 + r] = x0 * rs * lnw[lane];
                S[XN + (64 + lane) * 18 + r] = x1 * rs * lnw[64 + lane];
            }
        }
        __syncthreads();   // (b)

        const float* wl = ws + OFF_WT + l * (DM * DPROJ);

        // phase 2B: B/C/dt columns (acc2), waves 0-1 only; conv-BC + dt
        // immediately consume acc2 into LDS (BC2/DTT/AT) so acc2 dies
        // before phase 2X. Waves 2-3 skip straight to 2X.
        if (tid < 128) {
            float acc2[17];
            #pragma unroll
            for (int t = 0; t < 17; ++t) acc2[t] = 0.f;
            const bool has2 = (tid < 96);
            for (int d = 0; d < DM; ++d) {
                float w2 = has2 ? wl[d * DPROJ + 512 + tid] : 0.f;
                const float* xr = &S[XN + d * 18];
                #pragma unroll
                for (int tt = 0; tt < 8; ++tt) {
                    float2 p = *reinterpret_cast<const float2*>(xr + 2 * tt);
                    acc2[2*tt]   = fmaf(p.x, w2, acc2[2*tt]);
                    acc2[2*tt+1] = fmaf(p.y, w2, acc2[2*tt+1]);
                }
                acc2[16] = fmaf(xr[16], w2, acc2[16]);
            }
            if (tid < 64) {
                const float* cw = conv_w + l * 320 * 4;
                int c = 256 + tid;
                float k0 = cw[c * 4 + 0], k1 = cw[c * 4 + 1];
                float k2 = cw[c * 4 + 2], k3 = cw[c * 4 + 3];
                float bias = conv_b[l * 320 + c];
                #pragma unroll
                for (int t = 0; t < 17; ++t) {
                    float s = fmaf(acc2[t], k3, bias);
                    if (t >= 1) s = fmaf(acc2[t - 1], k2, s);
                    if (t >= 2) s = fmaf(acc2[t - 2], k1, s);
                    if (t >= 3) s = fmaf(acc2[t - 3], k0, s);
                    S[BC2 + t * 64 + tid] = siluf(s);
                }
            } else if (tid < 96) {
                int hh = tid - 64;
                float dtb = dt_bias[l * NH + hh];
                float eA = __expf(A_log[l * NH + hh]);
                #pragma unroll
                for (int t = 0; t < 17; ++t) {
                    float v = acc2[t] + dtb;
                    float dtv = (v > 15.f) ? v : log1pf(__expf(v));
                    S[DTT + hh * 17 + t] = dtv;
                    S[AT + hh * 17 + t] = __expf(-eA * dtv);
                }
            }
        }

        // phase 2X: xs columns (acc1), all threads
        float acc1[17];
        #pragma unroll
        for (int t = 0; t < 17; ++t) acc1[t] = 0.f;
        for (int d = 0; d < DM; ++d) {
            float w1 = wl[d * DPROJ + 256 + tid];
            const float* xr = &S[XN + d * 18];
            #pragma unroll
            for (int tt = 0; tt < 8; ++tt) {
                float2 p = *reinterpret_cast<const float2*>(xr + 2 * tt);
                acc1[2*tt]   = fmaf(p.x, w1, acc1[2*tt]);
                acc1[2*tt+1] = fmaf(p.y, w1, acc1[2*tt+1]);
            }
            acc1[16] = fmaf(xr[16], w1, acc1[16]);
        }
        // conv-xs IN PLACE (descending t: inputs t-3..t only overwritten
        // at indices > t) -> acc1 becomes silu(conv(xs)).
        {
            const float* cw = conv_w + l * 320 * 4;
            float k0 = cw[tid * 4 + 0], k1 = cw[tid * 4 + 1];
            float k2 = cw[tid * 4 + 2], k3 = cw[tid * 4 + 3];
            float bias = conv_b[l * 320 + tid];
            #pragma unroll
            for (int t = 16; t >= 0; --t) {
                float s = fmaf(acc1[t], k3, bias);
                if (t >= 1) s = fmaf(acc1[t - 1], k2, s);
                if (t >= 2) s = fmaf(acc1[t - 2], k1, s);
                if (t >= 3) s = fmaf(acc1[t - 3], k0, s);
                acc1[t] = siluf(s);
            }
        }
        __syncthreads();   // (c) BC2/DTT/AT visible to all

        // phase 4: selective scan, 4 passes x 8 states, D_skip/dt pre-folded.
        float y17[17];
        {
            const float Dsk = D_skip[l * NH + h];
            #pragma unroll
            for (int t = 0; t < 17; ++t) {
                y17[t] = acc1[t] * Dsk;              // D-skip term (uses xs)
                acc1[t] *= S[DTT + h * 17 + t];      // acc1 becomes xd
            }
        }
        #pragma unroll 1
        for (int qp = 0; qp < 4; ++qp) {
            float hst[8];
            #pragma unroll
            for (int n = 0; n < 8; ++n) hst[n] = 0.f;
            #pragma unroll
            for (int t = 0; t < 17; ++t) {
                float at = S[AT + h * 17 + t];
                float xd = acc1[t];
                float y = y17[t];
                const float4* bq = reinterpret_cast<const float4*>(&S[BC2 + t * 64]);
                {
                    float4 bb = bq[2 * qp];
                    hst[0] = fmaf(at, hst[0], xd * bb.x);
                    hst[1] = fmaf(at, hst[1], xd * bb.y);
                    hst[2] = fmaf(at, hst[2], xd * bb.z);
                    hst[3] = fmaf(at, hst[3], xd * bb.w);
                    float4 cc = bq[8 + 2 * qp];
                    y = fmaf(hst[0], cc.x, y);
                    y = fmaf(hst[1], cc.y, y);
                    y = fmaf(hst[2], cc.z, y);
                    y = fmaf(hst[3], cc.w, y);
                }
                {
                    float4 bb = bq[2 * qp + 1];
                    hst[4] = fmaf(at, hst[4], xd * bb.x);
                    hst[5] = fmaf(at, hst[5], xd * bb.y);
                    hst[6] = fmaf(at, hst[6], xd * bb.z);
                    hst[7] = fmaf(at, hst[7], xd * bb.w);
                    float4 cc = bq[8 + 2 * qp + 1];
                    y = fmaf(hst[4], cc.x, y);
                    y = fmaf(hst[5], cc.y, y);
                    y = fmaf(hst[6], cc.z, y);
                    y = fmaf(hst[7], cc.w, y);
                }
                y17[t] = y;
            }
        }

        // phase 2Z: z columns (acc0), all threads — XN is still valid
        // (disjoint from BC2/DTT/AT). acc1 is dead; only y17 carried.
        float acc0[17];
        #pragma unroll
        for (int t = 0; t < 17; ++t) acc0[t] = 0.f;
        for (int d = 0; d < DM; ++d) {
            float w0 = wl[d * DPROJ + tid];
            const float* xr = &S[XN + d * 18];
            #pragma unroll
            for (int tt = 0; tt < 8; ++tt) {
                float2 p = *reinterpret_cast<const float2*>(xr + 2 * tt);
                acc0[2*tt]   = fmaf(p.x, w0, acc0[2*tt]);
                acc0[2*tt+1] = fmaf(p.y, w0, acc0[2*tt+1]);
            }
            acc0[16] = fmaf(xr[16], w0, acc0[16]);
        }
        __syncthreads();   // (d) ALL XN + BC2/DTT/AT reads done -> G2 may overwrite

        // phase 5: G2 = silu(z) * y   (row tid, stride 18)
        #pragma unroll
        for (int t = 0; t < 17; ++t) {
            S[G2 + tid * 18 + t] = siluf(acc0[t]) * y17[t];
        }
        __syncthreads();   // (e)
        // phase 6: per-row sumsq -> scale G2 in place
        for (int r = wid; r < LSEQ; r += 4) {
            float g0 = S[G2 + lane * 18 + r];
            float g1 = S[G2 + (64 + lane) * 18 + r];
            float g2v = S[G2 + (128 + lane) * 18 + r];
            float g3 = S[G2 + (192 + lane) * 18 + r];
            float ss = g0 * g0 + g1 * g1 + g2v * g2v + g3 * g3;
            #pragma unroll
            for (int off = 1; off < 64; off <<= 1) ss += __shfl_xor(ss, off, 64);
            float rs = rsqrtf(ss * (1.f / 256.f) + EPSF);
            S[G2 + lane * 18 + r] = g0 * rs;
            S[G2 + (64 + lane) * 18 + r] = g1 * rs;
            S[G2 + (128 + lane) * 18 + r] = g2v * rs;
            S[G2 + (192 + lane) * 18 + r] = g3 * rs;
        }
        __syncthreads();   // (f)
        // phase 7: out_proj + residual
        {
            const int o = tid & 127;
            const int half = tid >> 7;
            const int t0 = half ? 8 : 0;
            float acc[9];
            #pragma unroll
            for (int k = 0; k < 9; ++k) acc[k] = 0.f;
            const float* ow = ws + OFF_OWT + l * (DINNER * DM);
            for (int in = 0; in < DINNER; ++in) {
                float w = ow[in * DM + o];
                const float* gr = &S[G2 + in * 18 + t0];
                float2 g0 = *reinterpret_cast<const float2*>(gr);
                float2 g1 = *reinterpret_cast<const float2*>(gr + 2);
                float2 g2v = *reinterpret_cast<const float2*>(gr + 4);
                float2 g3 = *reinterpret_cast<const float2*>(gr + 6);
                acc[0] = fmaf(g0.x, w, acc[0]); acc[1] = fmaf(g0.y, w, acc[1]);
                acc[2] = fmaf(g1.x, w, acc[2]); acc[3] = fmaf(g1.y, w, acc[3]);
                acc[4] = fmaf(g2v.x, w, acc[4]); acc[5] = fmaf(g2v.y, w, acc[5]);
                acc[6] = fmaf(g3.x, w, acc[6]); acc[7] = fmaf(g3.y, w, acc[7]);
                if (half) acc[8] = fmaf(gr[8], w, acc[8]);
            }
            #pragma unroll
            for (int k = 0; k < 8; ++k) {
                int t = t0 + k;
                S[XMAT + t * DM + o] += acc[k];
            }
            if (half) S[XMAT + 16 * DM + o] += acc[8];
        }
    }

    // ---------- epilogue ----------
    __syncthreads();
    for (int idx = tid; idx < LSEQ * DM; idx += 256) {
        int d = idx & 127;
        float te2 = fmaf(tf, time_w[256 + d], time_b[256 + d]);
        float te3 = fmaf(tf, time_w[384 + d], time_b[384 + d]);
        float se2 = fmaf(sv, short_w[256 + d], short_b[256 + d]);
        float se3 = fmaf(sv, short_w[384 + d], short_b[384 + d]);
        S[XN + idx] = S[XMAT + idx] * te2 * se2 + te3 + se3;
    }
    __syncthreads();
    {
        const float* outwT = ws + OFF_OUTWT;
        float* orow = out + (size_t)b * 16 * DIN;
        for (int idx = tid; idx < 16 * DIN; idx += 256) {
            int t1 = idx / DIN;
            int o = idx - t1 * DIN;
            float acc = output_b[o];
            const float* xr = &S[XN + (t1 + 1) * DM];
            for (int d = 0; d < DM; d += 4) {
                float4 xq = *reinterpret_cast<const float4*>(xr + d);
                acc = fmaf(xq.x, outwT[d * DIN + o], acc);
                acc = fmaf(xq.y, outwT[(d + 1) * DIN + o], acc);
                acc = fmaf(xq.z, outwT[(d + 2) * DIN + o], acc);
                acc = fmaf(xq.w, outwT[(d + 3) * DIN + o], acc);
            }
            orow[idx] = acc;
        }
    }
}

extern "C" void kernel_launch(void* const* d_in, const int* in_sizes, int n_in,
                              void* d_out, int out_size, void* d_ws, size_t ws_size,
                              hipStream_t stream) {
    (void)in_sizes; (void)n_in; (void)out_size; (void)ws_size;
    const float* init_states    = (const float*)d_in[0];
    const float* future_states  = (const float*)d_in[1];
    const float* time_flags     = (const float*)d_in[2];
    const float* shortcut_value = (const float*)d_in[3];
    const float* input_w        = (const float*)d_in[4];
    const float* input_b        = (const float*)d_in[5];
    const float* states_emb     = (const float*)d_in[6];
    const float* time_w         = (const float*)d_in[7];
    const float* time_b         = (const float*)d_in[8];
    const float* short_w        = (const float*)d_in[9];
    const float* short_b        = (const float*)d_in[10];
    const float* in_proj_w      = (const float*)d_in[11];
    const float* conv_w         = (const float*)d_in[12];
    const float* conv_b         = (const float*)d_in[13];
    const float* dt_bias        = (const float*)d_in[14];
    const float* A_log          = (const float*)d_in[15];
    const float* D_skip         = (const float*)d_in[16];
    const float* mixer_norm_w   = (const float*)d_in[17];
    const float* out_proj_w     = (const float*)d_in[18];
    const float* layer_norm_w   = (const float*)d_in[19];
    const float* output_w       = (const float*)d_in[20];
    const float* output_b       = (const float*)d_in[21];
    float* ws = (float*)d_ws;
    float* outp = (float*)d_out;

    prep_weights<<<(WS_TOTAL + 255) / 256, 256, 0, stream>>>(
        in_proj_w, out_proj_w, mixer_norm_w, input_w, output_w, ws);
    mamba_all<<<BATCH, 256, 0, stream>>>(
        init_states, future_states, time_flags, shortcut_value,
        input_b, states_emb, time_w, time_b, short_w, short_b,
        conv_w, conv_b, dt_bias, A_log, D_skip, layer_norm_w,
        output_b, ws, outp);
}

// Round 8
// 6518.478 us; speedup vs baseline: 1.4722x; 1.0651x over previous
//
#include <hip/hip_runtime.h>
#include <math.h>

// RewardGuidanceModel: 8-layer Mamba2 stack, B=4096, L=17, fully fused.
// One workgroup (256 thr) per batch element; all activations in LDS/regs.
// R11 = R10 + load-pipelining. R10 proved spill-free at the 64-VGPR cap
// (hbm_bytes 8.5GB -> 1.1GB structural) but VALUBusy stayed 33%: the
// projection loops issue ONE dependent L2 weight load (~200cy) per
// iteration with no unroll -> exposed latency dominates. Fix: unroll x4
// the four weight-streaming loops (2B/2X/2Z d-loops, phase-7 in-loop) so
// 4 loads are in flight; transient regs +4..6 in loops whose live set
// (~30) is far below the scan peak (~58) -> no spill risk.
// Everything else identical to R10 (27136B LDS, z recomputed after scan,
// phase order 2B -> 2X+conv -> scan -> 2Z -> G2).

#define BATCH 4096
#define LSEQ 17
#define DM 128
#define DIN 324
#define DINNER 256
#define DSTATE 32
#define NH 32
#define NL 8
#define DPROJ 608
#define EPSF 1e-5f

#define OFF_WT 0
#define SZ_WT (NL * DM * DPROJ)
#define OFF_OWT (OFF_WT + SZ_WT)
#define SZ_OWT (NL * DINNER * DM)
#define OFF_IWT (OFF_OWT + SZ_OWT)
#define SZ_IWT (DIN * 64)
#define OFF_OUTWT (OFF_IWT + SZ_IWT)
#define SZ_OUTWT (DM * DIN)
#define WS_TOTAL (OFF_OUTWT + SZ_OUTWT)

// LDS layout (floats). Region [2176, 6784) is time-shared:
//   phases 1-2Z: XN  (128 rows x stride 18 = 2304)  [2176, 4480)
//   phases 3-4 : BC2 (17*64=1088) DTT(544) AT(544)  [4480, 6656)
//   phases 5-7 : G2  (256 rows x stride 18 = 4608)  [2176, 6784)
// Barrier (d) separates ALL XN/BC2/DTT/AT reads from the G2 overwrite.
#define XMAT 0
#define XN   2176
#define G2   2176
#define BC2  4480
#define DTT  5568
#define AT   6112
#define STG  0
#define SMEM_TOT 6784

__device__ __forceinline__ float siluf(float x) { return x / (1.f + __expf(-x)); }

__global__ void prep_weights(const float* __restrict__ in_proj_w,
                             const float* __restrict__ out_proj_w,
                             const float* __restrict__ mixer_norm_w,
                             const float* __restrict__ input_w,
                             const float* __restrict__ output_w,
                             float* __restrict__ ws) {
    int idx = blockIdx.x * 256 + threadIdx.x;
    if (idx < SZ_WT) {
        int l = idx / (DM * DPROJ);
        int r = idx - l * (DM * DPROJ);
        int d = r / DPROJ, j = r - d * DPROJ;
        ws[OFF_WT + idx] = in_proj_w[(l * DPROJ + j) * DM + d];
    } else if (idx < OFF_IWT) {
        int r2 = idx - OFF_OWT;
        int l = r2 / (DINNER * DM);
        int r = r2 - l * (DINNER * DM);
        int in_ = r / DM, o = r - in_ * DM;
        ws[idx] = out_proj_w[(l * DM + o) * DINNER + in_] * mixer_norm_w[l * DINNER + in_];
    } else if (idx < OFF_OUTWT) {
        int r = idx - OFF_IWT;
        int d = r / 64, o = r - d * 64;
        ws[idx] = input_w[o * DIN + d];
    } else if (idx < WS_TOTAL) {
        int r = idx - OFF_OUTWT;
        int d = r / DIN, o = r - d * DIN;
        ws[idx] = output_w[o * DM + d];
    }
}

__global__ __launch_bounds__(256, 4)
void mamba_all(const float* __restrict__ ini, const float* __restrict__ fut,
               const float* __restrict__ tflag, const float* __restrict__ sval,
               const float* __restrict__ input_b, const float* __restrict__ states_emb,
               const float* __restrict__ time_w, const float* __restrict__ time_b,
               const float* __restrict__ short_w, const float* __restrict__ short_b,
               const float* __restrict__ conv_w, const float* __restrict__ conv_b,
               const float* __restrict__ dt_bias, const float* __restrict__ A_log,
               const float* __restrict__ D_skip, const float* __restrict__ layer_norm_w,
               const float* __restrict__ output_b, const float* __restrict__ ws,
               float* __restrict__ out) {
    __shared__ float S[SMEM_TOT];
    const int tid = threadIdx.x;
    const int b = blockIdx.x;
    const int lane = tid & 63;
    const int wid = tid >> 6;

    const float tf = tflag[b];
    const float sv = sval[b];

    // ---------- prologue: stage raw inputs ----------
    {
        const float* ir = ini + (size_t)b * DIN;
        const float* fr = fut + (size_t)b * 16 * DIN;
        for (int i = tid; i < DIN; i += 256) S[STG + i] = ir[i];
        for (int i = tid; i < 16 * DIN; i += 256) S[STG + DIN + i] = fr[i];
    }
    __syncthreads();
    // input projection (17x64); results in registers (STATIC k index),
    // written to XMAT after the barrier.
    float ipacc[5]; float ipemb[5];
    {
        const float* iwT = ws + OFF_IWT;
        #pragma unroll
        for (int k = 0; k < 5; ++k) {
            int idx = tid + k * 256;
            ipacc[k] = 0.f; ipemb[k] = 0.f;
            if (idx < LSEQ * 64) {
                int t = idx >> 6, o = idx & 63;
                float acc = input_b[o];
                const float* sr = &S[STG + t * DIN];
                for (int d = 0; d < DIN; d += 4) {
                    float4 sq = *reinterpret_cast<const float4*>(sr + d);
                    acc = fmaf(sq.x, iwT[d * 64 + o], acc);
                    acc = fmaf(sq.y, iwT[(d + 1) * 64 + o], acc);
                    acc = fmaf(sq.z, iwT[(d + 2) * 64 + o], acc);
                    acc = fmaf(sq.w, iwT[(d + 3) * 64 + o], acc);
                }
                ipacc[k] = acc;
                ipemb[k] = states_emb[t * 64 + o];
            }
        }
    }
    __syncthreads();
    {
        #pragma unroll
        for (int k = 0; k < 5; ++k) {
            int idx = tid + k * 256;
            if (idx < LSEQ * 64) {
                int t = idx >> 6, o = idx & 63;
                S[XMAT + t * DM + 64 + o] = ipacc[k];
                S[XMAT + t * DM + o] = ipemb[k];
            }
        }
    }
    __syncthreads();
    // te/se modulation (first halves)
    for (int idx = tid; idx < LSEQ * DM; idx += 256) {
        int d = idx & 127;
        float te0 = fmaf(tf, time_w[d], time_b[d]);
        float te1 = fmaf(tf, time_w[128 + d], time_b[128 + d]);
        float se0 = fmaf(sv, short_w[d], short_b[d]);
        float se1 = fmaf(sv, short_w[128 + d], short_b[128 + d]);
        S[XMAT + idx] = S[XMAT + idx] * te0 * se0 + te1 + se1;
    }

    const int h = tid >> 3;

    // ---------- 8 mamba2 layers ----------
    for (int l = 0; l < NL; ++l) {
        __syncthreads();   // (a) XMAT settled, prev-layer G2 reads done
        // phase 1: rmsnorm(x) -> XN [d][t] stride 18
        {
            const float* lnw = layer_norm_w + l * DM;
            for (int r = wid; r < LSEQ; r += 4) {
                float x0 = S[XMAT + r * DM + lane];
                float x1 = S[XMAT + r * DM + 64 + lane];
                float ss = x0 * x0 + x1 * x1;
                #pragma unroll
                for (int off = 1; off < 64; off <<= 1) ss += __shfl_xor(ss, off, 64);
                float rs = rsqrtf(ss * (1.f / 128.f) + EPSF);
                S[XN + lane * 18 + r] = x0 * rs * lnw[lane];
                S[XN + (64 + lane) * 18 + r] = x1 * rs * lnw[64 + lane];
            }
        }
        __syncthreads();   // (b)

        const float* wl = ws + OFF_WT + l * (DM * DPROJ);

        // phase 2B: B/C/dt columns (acc2), waves 0-1 only; conv-BC + dt
        // immediately consume acc2 into LDS (BC2/DTT/AT) so acc2 dies
        // before phase 2X. Waves 2-3 skip straight to 2X.
        if (tid < 128) {
            float acc2[17];
            #pragma unroll
            for (int t = 0; t < 17; ++t) acc2[t] = 0.f;
            const bool has2 = (tid < 96);
            #pragma unroll 4
            for (int d = 0; d < DM; ++d) {
                float w2 = has2 ? wl[d * DPROJ + 512 + tid] : 0.f;
                const float* xr = &S[XN + d * 18];
                #pragma unroll
                for (int tt = 0; tt < 8; ++tt) {
                    float2 p = *reinterpret_cast<const float2*>(xr + 2 * tt);
                    acc2[2*tt]   = fmaf(p.x, w2, acc2[2*tt]);
                    acc2[2*tt+1] = fmaf(p.y, w2, acc2[2*tt+1]);
                }
                acc2[16] = fmaf(xr[16], w2, acc2[16]);
            }
            if (tid < 64) {
                const float* cw = conv_w + l * 320 * 4;
                int c = 256 + tid;
                float k0 = cw[c * 4 + 0], k1 = cw[c * 4 + 1];
                float k2 = cw[c * 4 + 2], k3 = cw[c * 4 + 3];
                float bias = conv_b[l * 320 + c];
                #pragma unroll
                for (int t = 0; t < 17; ++t) {
                    float s = fmaf(acc2[t], k3, bias);
                    if (t >= 1) s = fmaf(acc2[t - 1], k2, s);
                    if (t >= 2) s = fmaf(acc2[t - 2], k1, s);
                    if (t >= 3) s = fmaf(acc2[t - 3], k0, s);
                    S[BC2 + t * 64 + tid] = siluf(s);
                }
            } else if (tid < 96) {
                int hh = tid - 64;
                float dtb = dt_bias[l * NH + hh];
                float eA = __expf(A_log[l * NH + hh]);
                #pragma unroll
                for (int t = 0; t < 17; ++t) {
                    float v = acc2[t] + dtb;
                    float dtv = (v > 15.f) ? v : log1pf(__expf(v));
                    S[DTT + hh * 17 + t] = dtv;
                    S[AT + hh * 17 + t] = __expf(-eA * dtv);
                }
            }
        }

        // phase 2X: xs columns (acc1), all threads
        float acc1[17];
        #pragma unroll
        for (int t = 0; t < 17; ++t) acc1[t] = 0.f;
        #pragma unroll 4
        for (int d = 0; d < DM; ++d) {
            float w1 = wl[d * DPROJ + 256 + tid];
            const float* xr = &S[XN + d * 18];
            #pragma unroll
            for (int tt = 0; tt < 8; ++tt) {
                float2 p = *reinterpret_cast<const float2*>(xr + 2 * tt);
                acc1[2*tt]   = fmaf(p.x, w1, acc1[2*tt]);
                acc1[2*tt+1] = fmaf(p.y, w1, acc1[2*tt+1]);
            }
            acc1[16] = fmaf(xr[16], w1, acc1[16]);
        }
        // conv-xs IN PLACE (descending t: inputs t-3..t only overwritten
        // at indices > t) -> acc1 becomes silu(conv(xs)).
        {
            const float* cw = conv_w + l * 320 * 4;
            float k0 = cw[tid * 4 + 0], k1 = cw[tid * 4 + 1];
            float k2 = cw[tid * 4 + 2], k3 = cw[tid * 4 + 3];
            float bias = conv_b[l * 320 + tid];
            #pragma unroll
            for (int t = 16; t >= 0; --t) {
                float s = fmaf(acc1[t], k3, bias);
                if (t >= 1) s = fmaf(acc1[t - 1], k2, s);
                if (t >= 2) s = fmaf(acc1[t - 2], k1, s);
                if (t >= 3) s = fmaf(acc1[t - 3], k0, s);
                acc1[t] = siluf(s);
            }
        }
        __syncthreads();   // (c) BC2/DTT/AT visible to all

        // phase 4: selective scan, 4 passes x 8 states, D_skip/dt pre-folded.
        float y17[17];
        {
            const float Dsk = D_skip[l * NH + h];
            #pragma unroll
            for (int t = 0; t < 17; ++t) {
                y17[t] = acc1[t] * Dsk;              // D-skip term (uses xs)
                acc1[t] *= S[DTT + h * 17 + t];      // acc1 becomes xd
            }
        }
        #pragma unroll 1
        for (int qp = 0; qp < 4; ++qp) {
            float hst[8];
            #pragma unroll
            for (int n = 0; n < 8; ++n) hst[n] = 0.f;
            #pragma unroll
            for (int t = 0; t < 17; ++t) {
                float at = S[AT + h * 17 + t];
                float xd = acc1[t];
                float y = y17[t];
                const float4* bq = reinterpret_cast<const float4*>(&S[BC2 + t * 64]);
                {
                    float4 bb = bq[2 * qp];
                    hst[0] = fmaf(at, hst[0], xd * bb.x);
                    hst[1] = fmaf(at, hst[1], xd * bb.y);
                    hst[2] = fmaf(at, hst[2], xd * bb.z);
                    hst[3] = fmaf(at, hst[3], xd * bb.w);
                    float4 cc = bq[8 + 2 * qp];
                    y = fmaf(hst[0], cc.x, y);
                    y = fmaf(hst[1], cc.y, y);
                    y = fmaf(hst[2], cc.z, y);
                    y = fmaf(hst[3], cc.w, y);
                }
                {
                    float4 bb = bq[2 * qp + 1];
                    hst[4] = fmaf(at, hst[4], xd * bb.x);
                    hst[5] = fmaf(at, hst[5], xd * bb.y);
                    hst[6] = fmaf(at, hst[6], xd * bb.z);
                    hst[7] = fmaf(at, hst[7], xd * bb.w);
                    float4 cc = bq[8 + 2 * qp + 1];
                    y = fmaf(hst[4], cc.x, y);
                    y = fmaf(hst[5], cc.y, y);
                    y = fmaf(hst[6], cc.z, y);
                    y = fmaf(hst[7], cc.w, y);
                }
                y17[t] = y;
            }
        }

        // phase 2Z: z columns (acc0), all threads — XN is still valid
        // (disjoint from BC2/DTT/AT). acc1 is dead; only y17 carried.
        float acc0[17];
        #pragma unroll
        for (int t = 0; t < 17; ++t) acc0[t] = 0.f;
        #pragma unroll 4
        for (int d = 0; d < DM; ++d) {
            float w0 = wl[d * DPROJ + tid];
            const float* xr = &S[XN + d * 18];
            #pragma unroll
            for (int tt = 0; tt < 8; ++tt) {
                float2 p = *reinterpret_cast<const float2*>(xr + 2 * tt);
                acc0[2*tt]   = fmaf(p.x, w0, acc0[2*tt]);
                acc0[2*tt+1] = fmaf(p.y, w0, acc0[2*tt+1]);
            }
            acc0[16] = fmaf(xr[16], w0, acc0[16]);
        }
        __syncthreads();   // (d) ALL XN + BC2/DTT/AT reads done -> G2 may overwrite

        // phase 5: G2 = silu(z) * y   (row tid, stride 18)
        #pragma unroll
        for (int t = 0; t < 17; ++t) {
            S[G2 + tid * 18 + t] = siluf(acc0[t]) * y17[t];
        }
        __syncthreads();   // (e)
        // phase 6: per-row sumsq -> scale G2 in place
        for (int r = wid; r < LSEQ; r += 4) {
            float g0 = S[G2 + lane * 18 + r];
            float g1 = S[G2 + (64 + lane) * 18 + r];
            float g2v = S[G2 + (128 + lane) * 18 + r];
            float g3 = S[G2 + (192 + lane) * 18 + r];
            float ss = g0 * g0 + g1 * g1 + g2v * g2v + g3 * g3;
            #pragma unroll
            for (int off = 1; off < 64; off <<= 1) ss += __shfl_xor(ss, off, 64);
            float rs = rsqrtf(ss * (1.f / 256.f) + EPSF);
            S[G2 + lane * 18 + r] = g0 * rs;
            S[G2 + (64 + lane) * 18 + r] = g1 * rs;
            S[G2 + (128 + lane) * 18 + r] = g2v * rs;
            S[G2 + (192 + lane) * 18 + r] = g3 * rs;
        }
        __syncthreads();   // (f)
        // phase 7: out_proj + residual
        {
            const int o = tid & 127;
            const int half = tid >> 7;
            const int t0 = half ? 8 : 0;
            float acc[9];
            #pragma unroll
            for (int k = 0; k < 9; ++k) acc[k] = 0.f;
            const float* ow = ws + OFF_OWT + l * (DINNER * DM);
            #pragma unroll 4
            for (int in = 0; in < DINNER; ++in) {
                float w = ow[in * DM + o];
                const float* gr = &S[G2 + in * 18 + t0];
                float2 g0 = *reinterpret_cast<const float2*>(gr);
                float2 g1 = *reinterpret_cast<const float2*>(gr + 2);
                float2 g2v = *reinterpret_cast<const float2*>(gr + 4);
                float2 g3 = *reinterpret_cast<const float2*>(gr + 6);
                acc[0] = fmaf(g0.x, w, acc[0]); acc[1] = fmaf(g0.y, w, acc[1]);
                acc[2] = fmaf(g1.x, w, acc[2]); acc[3] = fmaf(g1.y, w, acc[3]);
                acc[4] = fmaf(g2v.x, w, acc[4]); acc[5] = fmaf(g2v.y, w, acc[5]);
                acc[6] = fmaf(g3.x, w, acc[6]); acc[7] = fmaf(g3.y, w, acc[7]);
                if (half) acc[8] = fmaf(gr[8], w, acc[8]);
            }
            #pragma unroll
            for (int k = 0; k < 8; ++k) {
                int t = t0 + k;
                S[XMAT + t * DM + o] += acc[k];
            }
            if (half) S[XMAT + 16 * DM + o] += acc[8];
        }
    }

    // ---------- epilogue ----------
    __syncthreads();
    for (int idx = tid; idx < LSEQ * DM; idx += 256) {
        int d = idx & 127;
        float te2 = fmaf(tf, time_w[256 + d], time_b[256 + d]);
        float te3 = fmaf(tf, time_w[384 + d], time_b[384 + d]);
        float se2 = fmaf(sv, short_w[256 + d], short_b[256 + d]);
        float se3 = fmaf(sv, short_w[384 + d], short_b[384 + d]);
        S[XN + idx] = S[XMAT + idx] * te2 * se2 + te3 + se3;
    }
    __syncthreads();
    {
        const float* outwT = ws + OFF_OUTWT;
        float* orow = out + (size_t)b * 16 * DIN;
        for (int idx = tid; idx < 16 * DIN; idx += 256) {
            int t1 = idx / DIN;
            int o = idx - t1 * DIN;
            float acc = output_b[o];
            const float* xr = &S[XN + (t1 + 1) * DM];
            #pragma unroll 2
            for (int d = 0; d < DM; d += 4) {
                float4 xq = *reinterpret_cast<const float4*>(xr + d);
                acc = fmaf(xq.x, outwT[d * DIN + o], acc);
                acc = fmaf(xq.y, outwT[(d + 1) * DIN + o], acc);
                acc = fmaf(xq.z, outwT[(d + 2) * DIN + o], acc);
                acc = fmaf(xq.w, outwT[(d + 3) * DIN + o], acc);
            }
            orow[idx] = acc;
        }
    }
}

extern "C" void kernel_launch(void* const* d_in, const int* in_sizes, int n_in,
                              void* d_out, int out_size, void* d_ws, size_t ws_size,
                              hipStream_t stream) {
    (void)in_sizes; (void)n_in; (void)out_size; (void)ws_size;
    const float* init_states    = (const float*)d_in[0];
    const float* future_states  = (const float*)d_in[1];
    const float* time_flags     = (const float*)d_in[2];
    const float* shortcut_value = (const float*)d_in[3];
    const float* input_w        = (const float*)d_in[4];
    const float* input_b        = (const float*)d_in[5];
    const float* states_emb     = (const float*)d_in[6];
    const float* time_w         = (const float*)d_in[7];
    const float* time_b         = (const float*)d_in[8];
    const float* short_w        = (const float*)d_in[9];
    const float* short_b        = (const float*)d_in[10];
    const float* in_proj_w      = (const float*)d_in[11];
    const float* conv_w         = (const float*)d_in[12];
    const float* conv_b         = (const float*)d_in[13];
    const float* dt_bias        = (const float*)d_in[14];
    const float* A_log          = (const float*)d_in[15];
    const float* D_skip         = (const float*)d_in[16];
    const float* mixer_norm_w   = (const float*)d_in[17];
    const float* out_proj_w     = (const float*)d_in[18];
    const float* layer_norm_w   = (const float*)d_in[19];
    const float* output_w       = (const float*)d_in[20];
    const float* output_b       = (const float*)d_in[21];
    float* ws = (float*)d_ws;
    float* outp = (float*)d_out;

    prep_weights<<<(WS_TOTAL + 255) / 256, 256, 0, stream>>>(
        in_proj_w, out_proj_w, mixer_norm_w, input_w, output_w, ws);
    mamba_all<<<BATCH, 256, 0, stream>>>(
        init_states, future_states, time_flags, shortcut_value,
        input_b, states_emb, time_w, time_b, short_w, short_b,
        conv_w, conv_b, dt_bias, A_log, D_skip, layer_norm_w,
        output_b, ws, outp);
}

// Round 9
// 5968.652 us; speedup vs baseline: 1.6078x; 1.0921x over previous
//
#include <hip/hip_runtime.h>
#include <math.h>

// RewardGuidanceModel: 8-layer Mamba2 stack, B=4096, L=17, fully fused.
// One workgroup (256 thr) per batch element; all activations in LDS/regs.
// R12 = R11 + LDS-pipe diet. R11 is spill-free (hbm 0.23GB structural) but
// VALUBusy 36%: cycle audit says the broadcast ds_read stream saturates the
// per-CU LDS pipe (~150K cyc/block/layer; phase 7 alone ~39K). Changes:
//  - phase 7: 2 waves, col-per-thread, FULL-t acc[17] (halves p7 broadcast
//    instrs; same FMA total; waves 2-3 idle -> other 5 blocks fill SIMDs)
//  - phase 6: computes RS[17] only (no G2 in-place rewrite); phase 7
//    applies rs[t] at the end
//  - G2 stride 18 -> 17: gcd(17,32)=1 -> phase-6 column reads conflict-free;
//    frees room for RS at 6656 (temporally disjoint from AT [6112,6656):
//    AT dead after barrier (d), RS live (f)->(a)). SMEM_TOT stays 27136B
//    = 53 granules -> 6 blocks/CU preserved.
// Everything else identical to R11 (64-VGPR fit, z recomputed after scan,
// unroll-4 weight streams).

#define BATCH 4096
#define LSEQ 17
#define DM 128
#define DIN 324
#define DINNER 256
#define DSTATE 32
#define NH 32
#define NL 8
#define DPROJ 608
#define EPSF 1e-5f

#define OFF_WT 0
#define SZ_WT (NL * DM * DPROJ)
#define OFF_OWT (OFF_WT + SZ_WT)
#define SZ_OWT (NL * DINNER * DM)
#define OFF_IWT (OFF_OWT + SZ_OWT)
#define SZ_IWT (DIN * 64)
#define OFF_OUTWT (OFF_IWT + SZ_IWT)
#define SZ_OUTWT (DM * DIN)
#define WS_TOTAL (OFF_OUTWT + SZ_OUTWT)

// LDS layout (floats). Region [2176, 6784) is time-shared:
//   phases 1-2Z: XN  (128 rows x stride 18 = 2304)  [2176, 4480)
//   phases 3-4 : BC2 (17*64=1088) DTT(544) AT(544)  [4480, 6656)
//   phases 5-7 : G2  (256 rows x stride 17 = 4352)  [2176, 6528)
//                RS  (17)                           [6656, 6673)
// Barrier (d) separates ALL XN/BC2/DTT/AT reads from the G2 overwrite.
// RS overlaps AT's address range but not its lifetime.
#define XMAT 0
#define XN   2176
#define G2   2176
#define G2S  17
#define BC2  4480
#define DTT  5568
#define AT   6112
#define RSOF 6656
#define STG  0
#define SMEM_TOT 6784

__device__ __forceinline__ float siluf(float x) { return x / (1.f + __expf(-x)); }

__global__ void prep_weights(const float* __restrict__ in_proj_w,
                             const float* __restrict__ out_proj_w,
                             const float* __restrict__ mixer_norm_w,
                             const float* __restrict__ input_w,
                             const float* __restrict__ output_w,
                             float* __restrict__ ws) {
    int idx = blockIdx.x * 256 + threadIdx.x;
    if (idx < SZ_WT) {
        int l = idx / (DM * DPROJ);
        int r = idx - l * (DM * DPROJ);
        int d = r / DPROJ, j = r - d * DPROJ;
        ws[OFF_WT + idx] = in_proj_w[(l * DPROJ + j) * DM + d];
    } else if (idx < OFF_IWT) {
        int r2 = idx - OFF_OWT;
        int l = r2 / (DINNER * DM);
        int r = r2 - l * (DINNER * DM);
        int in_ = r / DM, o = r - in_ * DM;
        ws[idx] = out_proj_w[(l * DM + o) * DINNER + in_] * mixer_norm_w[l * DINNER + in_];
    } else if (idx < OFF_OUTWT) {
        int r = idx - OFF_IWT;
        int d = r / 64, o = r - d * 64;
        ws[idx] = input_w[o * DIN + d];
    } else if (idx < WS_TOTAL) {
        int r = idx - OFF_OUTWT;
        int d = r / DIN, o = r - d * DIN;
        ws[idx] = output_w[o * DM + d];
    }
}

__global__ __launch_bounds__(256, 4)
void mamba_all(const float* __restrict__ ini, const float* __restrict__ fut,
               const float* __restrict__ tflag, const float* __restrict__ sval,
               const float* __restrict__ input_b, const float* __restrict__ states_emb,
               const float* __restrict__ time_w, const float* __restrict__ time_b,
               const float* __restrict__ short_w, const float* __restrict__ short_b,
               const float* __restrict__ conv_w, const float* __restrict__ conv_b,
               const float* __restrict__ dt_bias, const float* __restrict__ A_log,
               const float* __restrict__ D_skip, const float* __restrict__ layer_norm_w,
               const float* __restrict__ output_b, const float* __restrict__ ws,
               float* __restrict__ out) {
    __shared__ float S[SMEM_TOT];
    const int tid = threadIdx.x;
    const int b = blockIdx.x;
    const int lane = tid & 63;
    const int wid = tid >> 6;

    const float tf = tflag[b];
    const float sv = sval[b];

    // ---------- prologue: stage raw inputs ----------
    {
        const float* ir = ini + (size_t)b * DIN;
        const float* fr = fut + (size_t)b * 16 * DIN;
        for (int i = tid; i < DIN; i += 256) S[STG + i] = ir[i];
        for (int i = tid; i < 16 * DIN; i += 256) S[STG + DIN + i] = fr[i];
    }
    __syncthreads();
    // input projection (17x64); results in registers (STATIC k index),
    // written to XMAT after the barrier.
    float ipacc[5]; float ipemb[5];
    {
        const float* iwT = ws + OFF_IWT;
        #pragma unroll
        for (int k = 0; k < 5; ++k) {
            int idx = tid + k * 256;
            ipacc[k] = 0.f; ipemb[k] = 0.f;
            if (idx < LSEQ * 64) {
                int t = idx >> 6, o = idx & 63;
                float acc = input_b[o];
                const float* sr = &S[STG + t * DIN];
                for (int d = 0; d < DIN; d += 4) {
                    float4 sq = *reinterpret_cast<const float4*>(sr + d);
                    acc = fmaf(sq.x, iwT[d * 64 + o], acc);
                    acc = fmaf(sq.y, iwT[(d + 1) * 64 + o], acc);
                    acc = fmaf(sq.z, iwT[(d + 2) * 64 + o], acc);
                    acc = fmaf(sq.w, iwT[(d + 3) * 64 + o], acc);
                }
                ipacc[k] = acc;
                ipemb[k] = states_emb[t * 64 + o];
            }
        }
    }
    __syncthreads();
    {
        #pragma unroll
        for (int k = 0; k < 5; ++k) {
            int idx = tid + k * 256;
            if (idx < LSEQ * 64) {
                int t = idx >> 6, o = idx & 63;
                S[XMAT + t * DM + 64 + o] = ipacc[k];
                S[XMAT + t * DM + o] = ipemb[k];
            }
        }
    }
    __syncthreads();
    // te/se modulation (first halves)
    for (int idx = tid; idx < LSEQ * DM; idx += 256) {
        int d = idx & 127;
        float te0 = fmaf(tf, time_w[d], time_b[d]);
        float te1 = fmaf(tf, time_w[128 + d], time_b[128 + d]);
        float se0 = fmaf(sv, short_w[d], short_b[d]);
        float se1 = fmaf(sv, short_w[128 + d], short_b[128 + d]);
        S[XMAT + idx] = S[XMAT + idx] * te0 * se0 + te1 + se1;
    }

    const int h = tid >> 3;

    // ---------- 8 mamba2 layers ----------
    for (int l = 0; l < NL; ++l) {
        __syncthreads();   // (a) XMAT settled, prev-layer G2/RS reads done
        // phase 1: rmsnorm(x) -> XN [d][t] stride 18
        {
            const float* lnw = layer_norm_w + l * DM;
            for (int r = wid; r < LSEQ; r += 4) {
                float x0 = S[XMAT + r * DM + lane];
                float x1 = S[XMAT + r * DM + 64 + lane];
                float ss = x0 * x0 + x1 * x1;
                #pragma unroll
                for (int off = 1; off < 64; off <<= 1) ss += __shfl_xor(ss, off, 64);
                float rs = rsqrtf(ss * (1.f / 128.f) + EPSF);
                S[XN + lane * 18 + r] = x0 * rs * lnw[lane];
                S[XN + (64 + lane) * 18 + r] = x1 * rs * lnw[64 + lane];
            }
        }
        __syncthreads();   // (b)

        const float* wl = ws + OFF_WT + l * (DM * DPROJ);

        // phase 2B: B/C/dt columns (acc2), waves 0-1 only; conv-BC + dt
        // immediately consume acc2 into LDS (BC2/DTT/AT).
        if (tid < 128) {
            float acc2[17];
            #pragma unroll
            for (int t = 0; t < 17; ++t) acc2[t] = 0.f;
            const bool has2 = (tid < 96);
            #pragma unroll 4
            for (int d = 0; d < DM; ++d) {
                float w2 = has2 ? wl[d * DPROJ + 512 + tid] : 0.f;
                const float* xr = &S[XN + d * 18];
                #pragma unroll
                for (int tt = 0; tt < 8; ++tt) {
                    float2 p = *reinterpret_cast<const float2*>(xr + 2 * tt);
                    acc2[2*tt]   = fmaf(p.x, w2, acc2[2*tt]);
                    acc2[2*tt+1] = fmaf(p.y, w2, acc2[2*tt+1]);
                }
                acc2[16] = fmaf(xr[16], w2, acc2[16]);
            }
            if (tid < 64) {
                const float* cw = conv_w + l * 320 * 4;
                int c = 256 + tid;
                float k0 = cw[c * 4 + 0], k1 = cw[c * 4 + 1];
                float k2 = cw[c * 4 + 2], k3 = cw[c * 4 + 3];
                float bias = conv_b[l * 320 + c];
                #pragma unroll
                for (int t = 0; t < 17; ++t) {
                    float s = fmaf(acc2[t], k3, bias);
                    if (t >= 1) s = fmaf(acc2[t - 1], k2, s);
                    if (t >= 2) s = fmaf(acc2[t - 2], k1, s);
                    if (t >= 3) s = fmaf(acc2[t - 3], k0, s);
                    S[BC2 + t * 64 + tid] = siluf(s);
                }
            } else if (tid < 96) {
                int hh = tid - 64;
                float dtb = dt_bias[l * NH + hh];
                float eA = __expf(A_log[l * NH + hh]);
                #pragma unroll
                for (int t = 0; t < 17; ++t) {
                    float v = acc2[t] + dtb;
                    float dtv = (v > 15.f) ? v : log1pf(__expf(v));
                    S[DTT + hh * 17 + t] = dtv;
                    S[AT + hh * 17 + t] = __expf(-eA * dtv);
                }
            }
        }

        // phase 2X: xs columns (acc1), all threads
        float acc1[17];
        #pragma unroll
        for (int t = 0; t < 17; ++t) acc1[t] = 0.f;
        #pragma unroll 4
        for (int d = 0; d < DM; ++d) {
            float w1 = wl[d * DPROJ + 256 + tid];
            const float* xr = &S[XN + d * 18];
            #pragma unroll
            for (int tt = 0; tt < 8; ++tt) {
                float2 p = *reinterpret_cast<const float2*>(xr + 2 * tt);
                acc1[2*tt]   = fmaf(p.x, w1, acc1[2*tt]);
                acc1[2*tt+1] = fmaf(p.y, w1, acc1[2*tt+1]);
            }
            acc1[16] = fmaf(xr[16], w1, acc1[16]);
        }
        // conv-xs IN PLACE (descending t) -> acc1 becomes silu(conv(xs)).
        {
            const float* cw = conv_w + l * 320 * 4;
            float k0 = cw[tid * 4 + 0], k1 = cw[tid * 4 + 1];
            float k2 = cw[tid * 4 + 2], k3 = cw[tid * 4 + 3];
            float bias = conv_b[l * 320 + tid];
            #pragma unroll
            for (int t = 16; t >= 0; --t) {
                float s = fmaf(acc1[t], k3, bias);
                if (t >= 1) s = fmaf(acc1[t - 1], k2, s);
                if (t >= 2) s = fmaf(acc1[t - 2], k1, s);
                if (t >= 3) s = fmaf(acc1[t - 3], k0, s);
                acc1[t] = siluf(s);
            }
        }
        __syncthreads();   // (c) BC2/DTT/AT visible to all

        // phase 4: selective scan, 4 passes x 8 states, D_skip/dt pre-folded.
        float y17[17];
        {
            const float Dsk = D_skip[l * NH + h];
            #pragma unroll
            for (int t = 0; t < 17; ++t) {
                y17[t] = acc1[t] * Dsk;              // D-skip term (uses xs)
                acc1[t] *= S[DTT + h * 17 + t];      // acc1 becomes xd
            }
        }
        #pragma unroll 1
        for (int qp = 0; qp < 4; ++qp) {
            float hst[8];
            #pragma unroll
            for (int n = 0; n < 8; ++n) hst[n] = 0.f;
            #pragma unroll
            for (int t = 0; t < 17; ++t) {
                float at = S[AT + h * 17 + t];
                float xd = acc1[t];
                float y = y17[t];
                const float4* bq = reinterpret_cast<const float4*>(&S[BC2 + t * 64]);
                {
                    float4 bb = bq[2 * qp];
                    hst[0] = fmaf(at, hst[0], xd * bb.x);
                    hst[1] = fmaf(at, hst[1], xd * bb.y);
                    hst[2] = fmaf(at, hst[2], xd * bb.z);
                    hst[3] = fmaf(at, hst[3], xd * bb.w);
                    float4 cc = bq[8 + 2 * qp];
                    y = fmaf(hst[0], cc.x, y);
                    y = fmaf(hst[1], cc.y, y);
                    y = fmaf(hst[2], cc.z, y);
                    y = fmaf(hst[3], cc.w, y);
                }
                {
                    float4 bb = bq[2 * qp + 1];
                    hst[4] = fmaf(at, hst[4], xd * bb.x);
                    hst[5] = fmaf(at, hst[5], xd * bb.y);
                    hst[6] = fmaf(at, hst[6], xd * bb.z);
                    hst[7] = fmaf(at, hst[7], xd * bb.w);
                    float4 cc = bq[8 + 2 * qp + 1];
                    y = fmaf(hst[4], cc.x, y);
                    y = fmaf(hst[5], cc.y, y);
                    y = fmaf(hst[6], cc.z, y);
                    y = fmaf(hst[7], cc.w, y);
                }
                y17[t] = y;
            }
        }

        // phase 2Z: z columns (acc0), all threads — XN still valid.
        float acc0[17];
        #pragma unroll
        for (int t = 0; t < 17; ++t) acc0[t] = 0.f;
        #pragma unroll 4
        for (int d = 0; d < DM; ++d) {
            float w0 = wl[d * DPROJ + tid];
            const float* xr = &S[XN + d * 18];
            #pragma unroll
            for (int tt = 0; tt < 8; ++tt) {
                float2 p = *reinterpret_cast<const float2*>(xr + 2 * tt);
                acc0[2*tt]   = fmaf(p.x, w0, acc0[2*tt]);
                acc0[2*tt+1] = fmaf(p.y, w0, acc0[2*tt+1]);
            }
            acc0[16] = fmaf(xr[16], w0, acc0[16]);
        }
        __syncthreads();   // (d) ALL XN + BC2/DTT/AT reads done -> G2 may overwrite

        // phase 5: G2 = silu(z) * y   (row tid, stride 17)
        #pragma unroll
        for (int t = 0; t < 17; ++t) {
            S[G2 + tid * G2S + t] = siluf(acc0[t]) * y17[t];
        }
        __syncthreads();   // (e)
        // phase 6: per-row sumsq -> RS[t] only (no G2 rewrite; stride 17
        // makes the column reads bank-conflict-free, gcd(17,32)=1)
        for (int r = wid; r < LSEQ; r += 4) {
            float g0 = S[G2 + lane * G2S + r];
            float g1 = S[G2 + (64 + lane) * G2S + r];
            float g2v = S[G2 + (128 + lane) * G2S + r];
            float g3 = S[G2 + (192 + lane) * G2S + r];
            float ss = g0 * g0 + g1 * g1 + g2v * g2v + g3 * g3;
            #pragma unroll
            for (int off = 1; off < 64; off <<= 1) ss += __shfl_xor(ss, off, 64);
            if (lane == 0) S[RSOF + r] = rsqrtf(ss * (1.f / 256.f) + EPSF);
        }
        __syncthreads();   // (f)
        // phase 7: out_proj + residual. 2 waves, one column per thread,
        // full t in registers: halves the broadcast ds_read instruction
        // stream vs the 4-wave half-t version. rs applied at the end.
        if (tid < 128) {
            const int o = tid;
            float acc[17];
            #pragma unroll
            for (int k = 0; k < 17; ++k) acc[k] = 0.f;
            const float* ow = ws + OFF_OWT + l * (DINNER * DM);
            #pragma unroll 2
            for (int in = 0; in < DINNER; ++in) {
                float w = ow[in * DM + o];
                const float* gr = &S[G2 + in * G2S];
                #pragma unroll
                for (int t = 0; t < 17; ++t) {
                    acc[t] = fmaf(gr[t], w, acc[t]);
                }
            }
            #pragma unroll
            for (int t = 0; t < 17; ++t) {
                S[XMAT + t * DM + o] += S[RSOF + t] * acc[t];
            }
        }
    }

    // ---------- epilogue ----------
    __syncthreads();
    for (int idx = tid; idx < LSEQ * DM; idx += 256) {
        int d = idx & 127;
        float te2 = fmaf(tf, time_w[256 + d], time_b[256 + d]);
        float te3 = fmaf(tf, time_w[384 + d], time_b[384 + d]);
        float se2 = fmaf(sv, short_w[256 + d], short_b[256 + d]);
        float se3 = fmaf(sv, short_w[384 + d], short_b[384 + d]);
        S[XN + idx] = S[XMAT + idx] * te2 * se2 + te3 + se3;
    }
    __syncthreads();
    {
        const float* outwT = ws + OFF_OUTWT;
        float* orow = out + (size_t)b * 16 * DIN;
        for (int idx = tid; idx < 16 * DIN; idx += 256) {
            int t1 = idx / DIN;
            int o = idx - t1 * DIN;
            float acc = output_b[o];
            const float* xr = &S[XN + (t1 + 1) * DM];
            #pragma unroll 2
            for (int d = 0; d < DM; d += 4) {
                float4 xq = *reinterpret_cast<const float4*>(xr + d);
                acc = fmaf(xq.x, outwT[d * DIN + o], acc);
                acc = fmaf(xq.y, outwT[(d + 1) * DIN + o], acc);
                acc = fmaf(xq.z, outwT[(d + 2) * DIN + o], acc);
                acc = fmaf(xq.w, outwT[(d + 3) * DIN + o], acc);
            }
            orow[idx] = acc;
        }
    }
}

extern "C" void kernel_launch(void* const* d_in, const int* in_sizes, int n_in,
                              void* d_out, int out_size, void* d_ws, size_t ws_size,
                              hipStream_t stream) {
    (void)in_sizes; (void)n_in; (void)out_size; (void)ws_size;
    const float* init_states    = (const float*)d_in[0];
    const float* future_states  = (const float*)d_in[1];
    const float* time_flags     = (const float*)d_in[2];
    const float* shortcut_value = (const float*)d_in[3];
    const float* input_w        = (const float*)d_in[4];
    const float* input_b        = (const float*)d_in[5];
    const float* states_emb     = (const float*)d_in[6];
    const float* time_w         = (const float*)d_in[7];
    const float* time_b         = (const float*)d_in[8];
    const float* short_w        = (const float*)d_in[9];
    const float* short_b        = (const float*)d_in[10];
    const float* in_proj_w      = (const float*)d_in[11];
    const float* conv_w         = (const float*)d_in[12];
    const float* conv_b         = (const float*)d_in[13];
    const float* dt_bias        = (const float*)d_in[14];
    const float* A_log          = (const float*)d_in[15];
    const float* D_skip         = (const float*)d_in[16];
    const float* mixer_norm_w   = (const float*)d_in[17];
    const float* out_proj_w     = (const float*)d_in[18];
    const float* layer_norm_w   = (const float*)d_in[19];
    const float* output_w       = (const float*)d_in[20];
    const float* output_b       = (const float*)d_in[21];
    float* ws = (float*)d_ws;
    float* outp = (float*)d_out;

    prep_weights<<<(WS_TOTAL + 255) / 256, 256, 0, stream>>>(
        in_proj_w, out_proj_w, mixer_norm_w, input_w, output_w, ws);
    mamba_all<<<BATCH, 256, 0, stream>>>(
        init_states, future_states, time_flags, shortcut_value,
        input_b, states_emb, time_w, time_b, short_w, short_b,
        conv_w, conv_b, dt_bias, A_log, D_skip, layer_norm_w,
        output_b, ws, outp);
}

// Round 10
// 4946.637 us; speedup vs baseline: 1.9400x; 1.2066x over previous
//
#include <hip/hip_runtime.h>
#include <math.h>

// RewardGuidanceModel: 8-layer Mamba2 stack, B=4096, L=17, fully fused.
// One workgroup (256 thr) per batch element; all activations in LDS/regs.
// R13 = R12 + two LDS-instruction-stream cuts (LDS pipe still saturated:
// ~13M of 15M cyc/CU in ds_read issue; R12's conflict fix 14.5M->5.4M
// confirmed the pipe theory).
//  1. G2 stride 17 -> 18 with RS stored in the row-padding slot
//     (S[G2 + r*18 + 17]): rows are 8B-aligned again so phase 7's 17-float
//     broadcast row-read emits b64 pairs (~9 instrs) instead of 17 b32
//     (stride 17 had broken alignment). RS costs zero space; SMEM stays
//     27136B -> 6 blocks/CU. Phase 6 columns become 4-way conflicts
//     (1.58x on ~200 instrs - accepted).
//  2. Phase 2B fused into 2X: waves 0-1 accumulate acc1 AND acc2 from ONE
//     XN broadcast stream (deletes 2304 LDS instrs/block/layer). Fused
//     path ~50-55 live regs (unroll 2) < 64. Scan untouched (R8's spill
//     was the 4x8-scan live-range extension, not fusion per se).
// Diagnostic: hbm_bytes must stay ~0.23 GB; if it balloons the fusion
// spilled -> revert next round.

#define BATCH 4096
#define LSEQ 17
#define DM 128
#define DIN 324
#define DINNER 256
#define DSTATE 32
#define NH 32
#define NL 8
#define DPROJ 608
#define EPSF 1e-5f

#define OFF_WT 0
#define SZ_WT (NL * DM * DPROJ)
#define OFF_OWT (OFF_WT + SZ_WT)
#define SZ_OWT (NL * DINNER * DM)
#define OFF_IWT (OFF_OWT + SZ_OWT)
#define SZ_IWT (DIN * 64)
#define OFF_OUTWT (OFF_IWT + SZ_IWT)
#define SZ_OUTWT (DM * DIN)
#define WS_TOTAL (OFF_OUTWT + SZ_OUTWT)

// LDS layout (floats). Region [2176, 6784) is time-shared:
//   phases 1-2Z: XN  (128 rows x stride 18 = 2304)  [2176, 4480)
//   phases 3-4 : BC2 (17*64=1088) DTT(544) AT(544)  [4480, 6656)
//   phases 5-7 : G2  (256 rows x stride 18 = 4608)  [2176, 6784)
//                RS[r] lives in G2 row-padding: S[G2 + r*18 + 17]
// Barrier (d) separates ALL XN/BC2/DTT/AT reads from the G2 overwrite.
#define XMAT 0
#define XN   2176
#define G2   2176
#define G2S  18
#define BC2  4480
#define DTT  5568
#define AT   6112
#define STG  0
#define SMEM_TOT 6784

__device__ __forceinline__ float siluf(float x) { return x / (1.f + __expf(-x)); }

__global__ void prep_weights(const float* __restrict__ in_proj_w,
                             const float* __restrict__ out_proj_w,
                             const float* __restrict__ mixer_norm_w,
                             const float* __restrict__ input_w,
                             const float* __restrict__ output_w,
                             float* __restrict__ ws) {
    int idx = blockIdx.x * 256 + threadIdx.x;
    if (idx < SZ_WT) {
        int l = idx / (DM * DPROJ);
        int r = idx - l * (DM * DPROJ);
        int d = r / DPROJ, j = r - d * DPROJ;
        ws[OFF_WT + idx] = in_proj_w[(l * DPROJ + j) * DM + d];
    } else if (idx < OFF_IWT) {
        int r2 = idx - OFF_OWT;
        int l = r2 / (DINNER * DM);
        int r = r2 - l * (DINNER * DM);
        int in_ = r / DM, o = r - in_ * DM;
        ws[idx] = out_proj_w[(l * DM + o) * DINNER + in_] * mixer_norm_w[l * DINNER + in_];
    } else if (idx < OFF_OUTWT) {
        int r = idx - OFF_IWT;
        int d = r / 64, o = r - d * 64;
        ws[idx] = input_w[o * DIN + d];
    } else if (idx < WS_TOTAL) {
        int r = idx - OFF_OUTWT;
        int d = r / DIN, o = r - d * DIN;
        ws[idx] = output_w[o * DM + d];
    }
}

__global__ __launch_bounds__(256, 4)
void mamba_all(const float* __restrict__ ini, const float* __restrict__ fut,
               const float* __restrict__ tflag, const float* __restrict__ sval,
               const float* __restrict__ input_b, const float* __restrict__ states_emb,
               const float* __restrict__ time_w, const float* __restrict__ time_b,
               const float* __restrict__ short_w, const float* __restrict__ short_b,
               const float* __restrict__ conv_w, const float* __restrict__ conv_b,
               const float* __restrict__ dt_bias, const float* __restrict__ A_log,
               const float* __restrict__ D_skip, const float* __restrict__ layer_norm_w,
               const float* __restrict__ output_b, const float* __restrict__ ws,
               float* __restrict__ out) {
    __shared__ float S[SMEM_TOT];
    const int tid = threadIdx.x;
    const int b = blockIdx.x;
    const int lane = tid & 63;
    const int wid = tid >> 6;

    const float tf = tflag[b];
    const float sv = sval[b];

    // ---------- prologue: stage raw inputs ----------
    {
        const float* ir = ini + (size_t)b * DIN;
        const float* fr = fut + (size_t)b * 16 * DIN;
        for (int i = tid; i < DIN; i += 256) S[STG + i] = ir[i];
        for (int i = tid; i < 16 * DIN; i += 256) S[STG + DIN + i] = fr[i];
    }
    __syncthreads();
    // input projection (17x64); results in registers (STATIC k index),
    // written to XMAT after the barrier.
    float ipacc[5]; float ipemb[5];
    {
        const float* iwT = ws + OFF_IWT;
        #pragma unroll
        for (int k = 0; k < 5; ++k) {
            int idx = tid + k * 256;
            ipacc[k] = 0.f; ipemb[k] = 0.f;
            if (idx < LSEQ * 64) {
                int t = idx >> 6, o = idx & 63;
                float acc = input_b[o];
                const float* sr = &S[STG + t * DIN];
                for (int d = 0; d < DIN; d += 4) {
                    float4 sq = *reinterpret_cast<const float4*>(sr + d);
                    acc = fmaf(sq.x, iwT[d * 64 + o], acc);
                    acc = fmaf(sq.y, iwT[(d + 1) * 64 + o], acc);
                    acc = fmaf(sq.z, iwT[(d + 2) * 64 + o], acc);
                    acc = fmaf(sq.w, iwT[(d + 3) * 64 + o], acc);
                }
                ipacc[k] = acc;
                ipemb[k] = states_emb[t * 64 + o];
            }
        }
    }
    __syncthreads();
    {
        #pragma unroll
        for (int k = 0; k < 5; ++k) {
            int idx = tid + k * 256;
            if (idx < LSEQ * 64) {
                int t = idx >> 6, o = idx & 63;
                S[XMAT + t * DM + 64 + o] = ipacc[k];
                S[XMAT + t * DM + o] = ipemb[k];
            }
        }
    }
    __syncthreads();
    // te/se modulation (first halves)
    for (int idx = tid; idx < LSEQ * DM; idx += 256) {
        int d = idx & 127;
        float te0 = fmaf(tf, time_w[d], time_b[d]);
        float te1 = fmaf(tf, time_w[128 + d], time_b[128 + d]);
        float se0 = fmaf(sv, short_w[d], short_b[d]);
        float se1 = fmaf(sv, short_w[128 + d], short_b[128 + d]);
        S[XMAT + idx] = S[XMAT + idx] * te0 * se0 + te1 + se1;
    }

    const int h = tid >> 3;

    // ---------- 8 mamba2 layers ----------
    for (int l = 0; l < NL; ++l) {
        __syncthreads();   // (a) XMAT settled, prev-layer G2/RS reads done
        // phase 1: rmsnorm(x) -> XN [d][t] stride 18
        {
            const float* lnw = layer_norm_w + l * DM;
            for (int r = wid; r < LSEQ; r += 4) {
                float x0 = S[XMAT + r * DM + lane];
                float x1 = S[XMAT + r * DM + 64 + lane];
                float ss = x0 * x0 + x1 * x1;
                #pragma unroll
                for (int off = 1; off < 64; off <<= 1) ss += __shfl_xor(ss, off, 64);
                float rs = rsqrtf(ss * (1.f / 128.f) + EPSF);
                S[XN + lane * 18 + r] = x0 * rs * lnw[lane];
                S[XN + (64 + lane) * 18 + r] = x1 * rs * lnw[64 + lane];
            }
        }
        __syncthreads();   // (b)

        const float* wl = ws + OFF_WT + l * (DM * DPROJ);

        // phase 2XB: fused xs + B/C/dt. Waves 0-1 accumulate acc1 AND acc2
        // from ONE XN broadcast stream; waves 2-3 accumulate acc1 only.
        float acc1[17];
        #pragma unroll
        for (int t = 0; t < 17; ++t) acc1[t] = 0.f;
        if (tid < 128) {
            float acc2[17];
            #pragma unroll
            for (int t = 0; t < 17; ++t) acc2[t] = 0.f;
            const bool has2 = (tid < 96);
            #pragma unroll 2
            for (int d = 0; d < DM; ++d) {
                float w1 = wl[d * DPROJ + 256 + tid];
                float w2 = has2 ? wl[d * DPROJ + 512 + tid] : 0.f;
                const float* xr = &S[XN + d * 18];
                #pragma unroll
                for (int tt = 0; tt < 8; ++tt) {
                    float2 p = *reinterpret_cast<const float2*>(xr + 2 * tt);
                    acc1[2*tt]   = fmaf(p.x, w1, acc1[2*tt]);
                    acc2[2*tt]   = fmaf(p.x, w2, acc2[2*tt]);
                    acc1[2*tt+1] = fmaf(p.y, w1, acc1[2*tt+1]);
                    acc2[2*tt+1] = fmaf(p.y, w2, acc2[2*tt+1]);
                }
                float x16 = xr[16];
                acc1[16] = fmaf(x16, w1, acc1[16]);
                acc2[16] = fmaf(x16, w2, acc2[16]);
            }
            if (tid < 64) {
                const float* cw = conv_w + l * 320 * 4;
                int c = 256 + tid;
                float k0 = cw[c * 4 + 0], k1 = cw[c * 4 + 1];
                float k2 = cw[c * 4 + 2], k3 = cw[c * 4 + 3];
                float bias = conv_b[l * 320 + c];
                #pragma unroll
                for (int t = 0; t < 17; ++t) {
                    float s = fmaf(acc2[t], k3, bias);
                    if (t >= 1) s = fmaf(acc2[t - 1], k2, s);
                    if (t >= 2) s = fmaf(acc2[t - 2], k1, s);
                    if (t >= 3) s = fmaf(acc2[t - 3], k0, s);
                    S[BC2 + t * 64 + tid] = siluf(s);
                }
            } else if (tid < 96) {
                int hh = tid - 64;
                float dtb = dt_bias[l * NH + hh];
                float eA = __expf(A_log[l * NH + hh]);
                #pragma unroll
                for (int t = 0; t < 17; ++t) {
                    float v = acc2[t] + dtb;
                    float dtv = (v > 15.f) ? v : log1pf(__expf(v));
                    S[DTT + hh * 17 + t] = dtv;
                    S[AT + hh * 17 + t] = __expf(-eA * dtv);
                }
            }
        } else {
            #pragma unroll 4
            for (int d = 0; d < DM; ++d) {
                float w1 = wl[d * DPROJ + 256 + tid];
                const float* xr = &S[XN + d * 18];
                #pragma unroll
                for (int tt = 0; tt < 8; ++tt) {
                    float2 p = *reinterpret_cast<const float2*>(xr + 2 * tt);
                    acc1[2*tt]   = fmaf(p.x, w1, acc1[2*tt]);
                    acc1[2*tt+1] = fmaf(p.y, w1, acc1[2*tt+1]);
                }
                acc1[16] = fmaf(xr[16], w1, acc1[16]);
            }
        }
        // conv-xs IN PLACE (descending t) -> acc1 becomes silu(conv(xs)).
        {
            const float* cw = conv_w + l * 320 * 4;
            float k0 = cw[tid * 4 + 0], k1 = cw[tid * 4 + 1];
            float k2 = cw[tid * 4 + 2], k3 = cw[tid * 4 + 3];
            float bias = conv_b[l * 320 + tid];
            #pragma unroll
            for (int t = 16; t >= 0; --t) {
                float s = fmaf(acc1[t], k3, bias);
                if (t >= 1) s = fmaf(acc1[t - 1], k2, s);
                if (t >= 2) s = fmaf(acc1[t - 2], k1, s);
                if (t >= 3) s = fmaf(acc1[t - 3], k0, s);
                acc1[t] = siluf(s);
            }
        }
        __syncthreads();   // (c) BC2/DTT/AT visible to all

        // phase 4: selective scan, 4 passes x 8 states, D_skip/dt pre-folded.
        float y17[17];
        {
            const float Dsk = D_skip[l * NH + h];
            #pragma unroll
            for (int t = 0; t < 17; ++t) {
                y17[t] = acc1[t] * Dsk;              // D-skip term (uses xs)
                acc1[t] *= S[DTT + h * 17 + t];      // acc1 becomes xd
            }
        }
        #pragma unroll 1
        for (int qp = 0; qp < 4; ++qp) {
            float hst[8];
            #pragma unroll
            for (int n = 0; n < 8; ++n) hst[n] = 0.f;
            #pragma unroll
            for (int t = 0; t < 17; ++t) {
                float at = S[AT + h * 17 + t];
                float xd = acc1[t];
                float y = y17[t];
                const float4* bq = reinterpret_cast<const float4*>(&S[BC2 + t * 64]);
                {
                    float4 bb = bq[2 * qp];
                    hst[0] = fmaf(at, hst[0], xd * bb.x);
                    hst[1] = fmaf(at, hst[1], xd * bb.y);
                    hst[2] = fmaf(at, hst[2], xd * bb.z);
                    hst[3] = fmaf(at, hst[3], xd * bb.w);
                    float4 cc = bq[8 + 2 * qp];
                    y = fmaf(hst[0], cc.x, y);
                    y = fmaf(hst[1], cc.y, y);
                    y = fmaf(hst[2], cc.z, y);
                    y = fmaf(hst[3], cc.w, y);
                }
                {
                    float4 bb = bq[2 * qp + 1];
                    hst[4] = fmaf(at, hst[4], xd * bb.x);
                    hst[5] = fmaf(at, hst[5], xd * bb.y);
                    hst[6] = fmaf(at, hst[6], xd * bb.z);
                    hst[7] = fmaf(at, hst[7], xd * bb.w);
                    float4 cc = bq[8 + 2 * qp + 1];
                    y = fmaf(hst[4], cc.x, y);
                    y = fmaf(hst[5], cc.y, y);
                    y = fmaf(hst[6], cc.z, y);
                    y = fmaf(hst[7], cc.w, y);
                }
                y17[t] = y;
            }
        }

        // phase 2Z: z columns (acc0), all threads — XN still valid.
        float acc0[17];
        #pragma unroll
        for (int t = 0; t < 17; ++t) acc0[t] = 0.f;
        #pragma unroll 4
        for (int d = 0; d < DM; ++d) {
            float w0 = wl[d * DPROJ + tid];
            const float* xr = &S[XN + d * 18];
            #pragma unroll
            for (int tt = 0; tt < 8; ++tt) {
                float2 p = *reinterpret_cast<const float2*>(xr + 2 * tt);
                acc0[2*tt]   = fmaf(p.x, w0, acc0[2*tt]);
                acc0[2*tt+1] = fmaf(p.y, w0, acc0[2*tt+1]);
            }
            acc0[16] = fmaf(xr[16], w0, acc0[16]);
        }
        __syncthreads();   // (d) ALL XN + BC2/DTT/AT reads done -> G2 may overwrite

        // phase 5: G2 = silu(z) * y   (row tid, stride 18)
        #pragma unroll
        for (int t = 0; t < 17; ++t) {
            S[G2 + tid * G2S + t] = siluf(acc0[t]) * y17[t];
        }
        __syncthreads();   // (e)
        // phase 6: per-row sumsq -> RS in row-padding slot G2 + r*18 + 17.
        // Column reads at stride 18 are a 4-way conflict (1.58x, ~200 instrs).
        for (int r = wid; r < LSEQ; r += 4) {
            float g0 = S[G2 + lane * G2S + r];
            float g1 = S[G2 + (64 + lane) * G2S + r];
            float g2v = S[G2 + (128 + lane) * G2S + r];
            float g3 = S[G2 + (192 + lane) * G2S + r];
            float ss = g0 * g0 + g1 * g1 + g2v * g2v + g3 * g3;
            #pragma unroll
            for (int off = 1; off < 64; off <<= 1) ss += __shfl_xor(ss, off, 64);
            if (lane == 0) S[G2 + r * G2S + 17] = rsqrtf(ss * (1.f / 256.f) + EPSF);
        }
        __syncthreads();   // (f)
        // phase 7: out_proj + residual. 2 waves, one column per thread,
        // full t in registers; 8B-aligned G2 rows -> b64-pair reads.
        if (tid < 128) {
            const int o = tid;
            float acc[17];
            #pragma unroll
            for (int k = 0; k < 17; ++k) acc[k] = 0.f;
            const float* ow = ws + OFF_OWT + l * (DINNER * DM);
            #pragma unroll 2
            for (int in = 0; in < DINNER; ++in) {
                float w = ow[in * DM + o];
                const float* gr = &S[G2 + in * G2S];
                #pragma unroll
                for (int tt = 0; tt < 8; ++tt) {
                    float2 p = *reinterpret_cast<const float2*>(gr + 2 * tt);
                    acc[2*tt]   = fmaf(p.x, w, acc[2*tt]);
                    acc[2*tt+1] = fmaf(p.y, w, acc[2*tt+1]);
                }
                acc[16] = fmaf(gr[16], w, acc[16]);
            }
            #pragma unroll
            for (int t = 0; t < 17; ++t) {
                S[XMAT + t * DM + o] += S[G2 + t * G2S + 17] * acc[t];
            }
        }
    }

    // ---------- epilogue ----------
    __syncthreads();
    for (int idx = tid; idx < LSEQ * DM; idx += 256) {
        int d = idx & 127;
        float te2 = fmaf(tf, time_w[256 + d], time_b[256 + d]);
        float te3 = fmaf(tf, time_w[384 + d], time_b[384 + d]);
        float se2 = fmaf(sv, short_w[256 + d], short_b[256 + d]);
        float se3 = fmaf(sv, short_w[384 + d], short_b[384 + d]);
        S[XN + idx] = S[XMAT + idx] * te2 * se2 + te3 + se3;
    }
    __syncthreads();
    {
        const float* outwT = ws + OFF_OUTWT;
        float* orow = out + (size_t)b * 16 * DIN;
        for (int idx = tid; idx < 16 * DIN; idx += 256) {
            int t1 = idx / DIN;
            int o = idx - t1 * DIN;
            float acc = output_b[o];
            const float* xr = &S[XN + (t1 + 1) * DM];
            #pragma unroll 2
            for (int d = 0; d < DM; d += 4) {
                float4 xq = *reinterpret_cast<const float4*>(xr + d);
                acc = fmaf(xq.x, outwT[d * DIN + o], acc);
                acc = fmaf(xq.y, outwT[(d + 1) * DIN + o], acc);
                acc = fmaf(xq.z, outwT[(d + 2) * DIN + o], acc);
                acc = fmaf(xq.w, outwT[(d + 3) * DIN + o], acc);
            }
            orow[idx] = acc;
        }
    }
}

extern "C" void kernel_launch(void* const* d_in, const int* in_sizes, int n_in,
                              void* d_out, int out_size, void* d_ws, size_t ws_size,
                              hipStream_t stream) {
    (void)in_sizes; (void)n_in; (void)out_size; (void)ws_size;
    const float* init_states    = (const float*)d_in[0];
    const float* future_states  = (const float*)d_in[1];
    const float* time_flags     = (const float*)d_in[2];
    const float* shortcut_value = (const float*)d_in[3];
    const float* input_w        = (const float*)d_in[4];
    const float* input_b        = (const float*)d_in[5];
    const float* states_emb     = (const float*)d_in[6];
    const float* time_w         = (const float*)d_in[7];
    const float* time_b         = (const float*)d_in[8];
    const float* short_w        = (const float*)d_in[9];
    const float* short_b        = (const float*)d_in[10];
    const float* in_proj_w      = (const float*)d_in[11];
    const float* conv_w         = (const float*)d_in[12];
    const float* conv_b         = (const float*)d_in[13];
    const float* dt_bias        = (const float*)d_in[14];
    const float* A_log          = (const float*)d_in[15];
    const float* D_skip         = (const float*)d_in[16];
    const float* mixer_norm_w   = (const float*)d_in[17];
    const float* out_proj_w     = (const float*)d_in[18];
    const float* layer_norm_w   = (const float*)d_in[19];
    const float* output_w       = (const float*)d_in[20];
    const float* output_b       = (const float*)d_in[21];
    float* ws = (float*)d_ws;
    float* outp = (float*)d_out;

    prep_weights<<<(WS_TOTAL + 255) / 256, 256, 0, stream>>>(
        in_proj_w, out_proj_w, mixer_norm_w, input_w, output_w, ws);
    mamba_all<<<BATCH, 256, 0, stream>>>(
        init_states, future_states, time_flags, shortcut_value,
        input_b, states_emb, time_w, time_b, short_w, short_b,
        conv_w, conv_b, dt_bias, A_log, D_skip, layer_norm_w,
        output_b, ws, outp);
}